// Round 7
// baseline (340.620 us; speedup 1.0000x reference)
//
#include <hip/hip_runtime.h>
#include <hip/hip_bf16.h>
#include <math.h>

// RGA module: B=64, C=128, HW=784, IC=32, IS=196, DS=49, DC=8.
// Rank-32 factorization removes Gs [b,784,784] and Gc [b,128,128] entirely.
// R5: k8 on MFMA. R7: k4 spatial chain fully on MFMA.
// R8: k10 split into s-chunk partials (896 blocks) + reduce.
// R9: k1+k2 fused into one LDS-tiled f32 GEMM (k1k2_tile).
// R10: k3 ported to the k8 MFMA template; theta/phi stored bf16 (thph).
// R11: k8 re-gridded (3 'which' GEMMs merged, 832 blocks, XCD-swizzled b).
// R12: k9 rebuilt (LDS-transposed weights, 60.5us -> ~8us).
// R13: k1k2 ported to MFMA (45us -> ~12us).
// R14: k4 staging de-scalarized via acomb (k3 emits k4's Al layout).
// R15: k8 LDS/barrier-free. B-fragments (x1 rows) have zero intra-block
//      reuse -- global->LDS->ds_read was pure overhead with identical
//      coalescing; A-fragments L1-shared across waves. All 50 barriers gone.
//      k4's Al LDS also dropped (acomb fragments direct from global, L1);
//      k3 zeroes acomb pad rows 196-207 (k4's staging used to do it).
//      MFMA operands bit-identical.

#define BB 64
#define CC 128
#define HW 784
#define IC 32
#define IS 196
#define DS 49

// ---- wf (converted f32 inputs) offsets, padded to 4-float alignment ----
#define O_THW 0
#define O_PHW 4096
#define O_GGSW 8192
#define O_GXSW 315520
#define O_WS1W 319616
#define O_WS2W 329272
#define O_THCW 329324
#define O_PHCW 482988
#define O_GGCW 636652
#define O_GXCW 644844
#define O_WC1W 798508
#define O_WC2W 798772
#define O_THS 798780
#define O_THB 798812
#define O_PHS 798844
#define O_PHB 798876
#define O_GGSS 798908
#define O_GGSB 799104
#define O_GXSS 799300
#define O_GXSB 799332
#define O_WS1S 799364
#define O_WS1B 799416
#define O_WS2S 799468
#define O_WS2B 799472
#define O_THCS 799476
#define O_THCB 799672
#define O_PHCS 799868
#define O_PHCB 800064
#define O_GGCS 800260
#define O_GGCB 800292
#define O_GXCS 800324
#define O_GXCB 800520
#define O_WC1S 800716
#define O_WC1B 800724
#define O_WC2S 800732
#define O_WC2B 800736
#define WF_TOTAL 800768

static const int SRC_SIZES[36] = {
  4096,4096,307328,4096,9653,49,153664,153664,8192,153664,264,8,
  32,32,32,32,196,196,32,32,49,49,1,1,196,196,196,196,32,32,196,196,8,8,1,1};
static const int DST_OFF[36] = {
  O_THW,O_PHW,O_GGSW,O_GXSW,O_WS1W,O_WS2W,O_THCW,O_PHCW,O_GGCW,O_GXCW,O_WC1W,O_WC2W,
  O_THS,O_THB,O_PHS,O_PHB,O_GGSS,O_GGSB,O_GXSS,O_GXSB,O_WS1S,O_WS1B,O_WS2S,O_WS2B,
  O_THCS,O_THCB,O_PHCS,O_PHCB,O_GGCS,O_GGCB,O_GXCS,O_GXCB,O_WC1S,O_WC1B,O_WC2S,O_WC2B};

struct ConvArgs { const void* p[36]; int cum[37]; int dst[36]; };

typedef __attribute__((ext_vector_type(8))) short short8;   // 8 bf16 (4 VGPRs)
typedef __attribute__((ext_vector_type(4))) float fragf4;   // MFMA C/D

union FragU { unsigned int w[4]; short8 s8; };

__device__ __forceinline__ float sigf(float v){ return 1.0f/(1.0f+expf(-v)); }
__device__ __forceinline__ float hb2f(unsigned short h){ return __uint_as_float(((unsigned)h)<<16); }
__device__ __forceinline__ unsigned short f2hb(float v){
  __hip_bfloat16 hb = __float2bfloat16(v);
  return *reinterpret_cast<unsigned short*>(&hb);
}
__device__ __forceinline__ float loadx(const void* x, int flag, size_t idx){
  if (flag) return hb2f(((const unsigned short*)x)[idx]);
  return ((const float*)x)[idx];
}
__device__ __forceinline__ short8 zero8(){
  FragU z; z.w[0]=0u; z.w[1]=0u; z.w[2]=0u; z.w[3]=0u; return z.s8;
}

// ---- kd: dtype probe. bf16 data -> ~all sane exponents; f32-misread -> ~62%.
__global__ void kd_detect(const void* x, int* flag){
  __shared__ int cnt[256];
  int t = threadIdx.x;
  const unsigned short* h = (const unsigned short*)x;
  int c = 0;
  for (int k=0;k<4;k++){
    unsigned short v = h[t*4+k];
    int e = (v>>7)&0xFF;
    c += (e==0 || (e>=97 && e<=157)) ? 1 : 0;
  }
  cnt[t] = c;
  __syncthreads();
  for (int s=128; s; s>>=1){ if (t<s) cnt[t]+=cnt[t+s]; __syncthreads(); }
  if (t==0) *flag = (cnt[0] >= 973) ? 1 : 0;
}

// ---- kc: convert all non-x inputs to f32 arena wf
__global__ void kc_convert(ConvArgs a, const int* flagp, float* wf){
  int flag = *flagp;
  int g = blockIdx.x*256 + threadIdx.x;
  if (g >= a.cum[36]) return;
  int i = 0;
  while (g >= a.cum[i+1]) i++;
  int local = g - a.cum[i];
  float v;
  if (flag) v = hb2f(((const unsigned short*)a.p[i])[local]);
  else      v = ((const float*)a.p[i])[local];
  wf[a.dst[i] + local] = v;
}

// ---- kw: bf16 copies of thc/phc/gxc weights + ggs_w halves + wthph[96][128]
#define KW_TOT (5*IS*HW + 96*CC)
__global__ void kw_wbf(const float* wf, unsigned short* wbf){
  int i = blockIdx.x*256 + threadIdx.x;
  if (i >= KW_TOT) return;
  float v;
  if (i < 3*IS*HW){
    int which = i/(IS*HW), r = i - which*(IS*HW);
    int off = which==0?O_THCW:(which==1?O_PHCW:O_GXCW);
    v = wf[off + r];
  } else if (i < 5*IS*HW){
    int which = i/(IS*HW), r = i - which*(IS*HW);
    int row = r/HW, col = r - row*HW;
    v = wf[O_GGSW + row*(2*HW) + (which-3)*HW + col];
  } else {
    int r = i - 5*IS*HW;               // 0..12287
    int row = r >> 7, col = r & 127;   // th 0-31, ph 32-63 (contig at wf+0), gxs 64-95
    v = (row < 64) ? wf[row*CC + col] : wf[O_GXSW + (row-64)*CC + col];
  }
  wbf[i] = f2hb(v);
}

// ---- k0: ws1bf [64][224] bf16 (zero-padded W1aug: col0 = gx weight)
__global__ void k0_ws1bf(const float* wf, unsigned int* ws1bf32){
  int i = blockIdx.x*256 + threadIdx.x;      // 64*112 u32
  if (i >= 64*112) return;
  int o2 = i/112, k2 = i - o2*112;
  int k = k2*2;
  float v0 = (o2<DS && k<197)   ? wf[O_WS1W + o2*197 + k]   : 0.f;
  float v1 = (o2<DS && k+1<197) ? wf[O_WS1W + o2*197 + k+1] : 0.f;
  ws1bf32[i] = (unsigned)f2hb(v0) | ((unsigned)f2hb(v1)<<16);
}

// ---- k1k2 v3 (R13, MFMA): theta/phi/g_xs projections.
#define XST 68   // Xl u32 stride per p-row (272B: 16B-aligned b128 reads)
__global__ __launch_bounds__(256) void k1k2_mfma(const void* x, const int* flagp,
    const float* wf, const unsigned short* wthph, unsigned short* thph, float* g_xs)
{
  __shared__ __align__(16) unsigned int Xl[64*XST];   // 17.4 KB
  int flag = *flagp;
  int t = threadIdx.x;
  int pt = blockIdx.x % 13, b = blockIdx.x / 13;
  int p0 = pt*64;

  // stage x^T tile: Xl[p][c] bf16 via 2x2 transpose micro-tiles (8 units/thread)
  #pragma unroll
  for (int k=0; k<8; k++){
    int idx = k*256 + t;
    int q = idx & 31;              // p-pair (coalesced across lanes)
    int c2 = idx >> 5;             // c-pair, 0..63
    int p = p0 + 2*q, c = 2*c2;
    unsigned int w0 = 0u, w1 = 0u;
    if (p < HW){                   // HW even, p even -> p+1 < HW too
      if (flag){
        const unsigned short* xb = (const unsigned short*)x + (size_t)b*CC*HW;
        unsigned int a0 = *(const unsigned int*)(xb + (size_t)c*HW + p);
        unsigned int a1 = *(const unsigned int*)(xb + (size_t)(c+1)*HW + p);
        w0 = (a0 & 0xffffu) | (a1 << 16);
        w1 = (a0 >> 16) | (a1 & 0xffff0000u);
      } else {
        const float* xb = (const float*)x + (size_t)b*CC*HW;
        float2 a0 = *(const float2*)(xb + (size_t)c*HW + p);
        float2 a1 = *(const float2*)(xb + (size_t)(c+1)*HW + p);
        w0 = (unsigned)f2hb(a0.x) | ((unsigned)f2hb(a1.x)<<16);
        w1 = (unsigned)f2hb(a0.y) | ((unsigned)f2hb(a1.y)<<16);
      }
    }
    Xl[(2*q+0)*XST + c2] = w0;
    Xl[(2*q+1)*XST + c2] = w1;
  }
  __syncthreads();

  int lane = t & 63, w = t >> 6;
  int m16 = lane & 15, kq = lane >> 4;
  fragf4 acc[6];
  #pragma unroll
  for (int mt=0; mt<6; mt++)
    #pragma unroll
    for (int r=0;r<4;r++) acc[mt][r] = 0.f;

  const unsigned short* Xu = (const unsigned short*)Xl;
  #pragma unroll
  for (int kk=0; kk<4; kk++){
    short8 bfr = *(const short8*)(Xu + (w*16+m16)*(2*XST) + kk*32 + kq*8);
    #pragma unroll
    for (int mt=0; mt<6; mt++){
      short8 af = *(const short8*)(wthph + (mt*16+m16)*CC + kk*32 + kq*8);
      acc[mt] = __builtin_amdgcn_mfma_f32_16x16x32_bf16(af, bfr, acc[mt], 0,0,0);
    }
  }

  int p = p0 + w*16 + m16;
  // theta/phi epilogue: o = mt*16 + kq*4 + r in [0,64)
  #pragma unroll
  for (int mt=0; mt<4; mt++){
    #pragma unroll
    for (int r=0;r<4;r++){
      int o = mt*16 + kq*4 + r;
      float sc = (o<32) ? wf[O_THS+o] : wf[O_PHS+o-32];
      float sh = (o<32) ? wf[O_THB+o] : wf[O_PHB+o-32];
      float v = fmaxf(sc*acc[mt][r] + sh, 0.f);
      if (p < HW) thph[((size_t)b*64 + o)*HW + p] = f2hb(v);
    }
  }
  // gxs epilogue: relu'd rows 64..95, mean over o via kq-lane reduce
  float gs = 0.f;
  #pragma unroll
  for (int mt=4; mt<6; mt++){
    #pragma unroll
    for (int r=0;r<4;r++){
      int o = (mt-4)*16 + kq*4 + r;
      gs += fmaxf(wf[O_GXSS+o]*acc[mt][r] + wf[O_GXSB+o], 0.f);
    }
  }
  gs += __shfl_xor(gs, 16);
  gs += __shfl_xor(gs, 32);
  if (kq == 0 && p < HW) g_xs[(size_t)b*HW + p] = gs*(1.f/32.f);
}

// ---- k3 v5 (R15, MFMA): writes acomb[b][208][64] bf16 in k4's Al row layout:
//      row o = [Aphi[o][c=0..31] | Atheta[o][c=0..31]]. Pad rows 196-207 are
//      ZEROED (k4 reads acomb fragments directly; NaN-safe).
#define K3ST 40
__global__ __launch_bounds__(256) void k3_mfma(const unsigned short* wggs,
    const unsigned short* thph, unsigned short* acomb)
{
  __shared__ __align__(16) unsigned short Al[112*K3ST];
  __shared__ __align__(16) unsigned short Bl[32*K3ST];
  int t = threadIdx.x;
  int mh = blockIdx.x & 1;
  int b  = (blockIdx.x >> 1) & 63;
  int which = blockIdx.x >> 7;
  int m0 = mh*112;
  const unsigned short* wsrc = wggs + (size_t)which*IS*HW;
  const unsigned short* ssrc = thph + ((size_t)b*64 + (which ? 0 : 32))*HW;
  int lane = t & 63, w = t >> 6;
  int m16 = lane & 15, kq = lane >> 4;
  fragf4 acc[2][2];
  #pragma unroll
  for (int i=0;i<2;i++)
    #pragma unroll
    for (int nt=0;nt<2;nt++)
      #pragma unroll
      for (int r=0;r<4;r++) acc[i][nt][r] = 0.f;

  for (int kk=0; kk<25; kk++){
    int p0 = kk*32;
    __syncthreads();
    for (int i=t; i<112*4; i+=256){
      int row = i>>2, q = i&3;
      uint4 v = make_uint4(0u,0u,0u,0u);
      int gr = m0 + row, p = p0 + q*8;
      if (gr < IS && p+8 <= HW)
        v = *(const uint4*)(wsrc + (size_t)gr*HW + p);
      *(uint4*)(Al + row*K3ST + q*8) = v;
    }
    if (t < 128){
      int row = t>>2, q = t&3;
      uint4 v = make_uint4(0u,0u,0u,0u);
      int p = p0 + q*8;
      if (p+8 <= HW)
        v = *(const uint4*)(ssrc + (size_t)row*HW + p);
      *(uint4*)(Bl + row*K3ST + q*8) = v;
    }
    __syncthreads();
    short8 bfr[2];
    #pragma unroll
    for (int nt=0;nt<2;nt++)
      bfr[nt] = *(const short8*)(Bl + (nt*16+m16)*K3ST + kq*8);
    #pragma unroll
    for (int i=0;i<2;i++){
      int mt = w + 4*i;
      if (mt < 7){
        short8 af = *(const short8*)(Al + (mt*16+m16)*K3ST + kq*8);
        acc[i][0] = __builtin_amdgcn_mfma_f32_16x16x32_bf16(af, bfr[0], acc[i][0], 0,0,0);
        acc[i][1] = __builtin_amdgcn_mfma_f32_16x16x32_bf16(af, bfr[1], acc[i][1], 0,0,0);
      }
    }
  }
  unsigned short* dst = acomb + (size_t)b*208*64 + which*32;
  #pragma unroll
  for (int i=0;i<2;i++){
    int mt = w + 4*i;
    if (mt >= 7) continue;
    #pragma unroll
    for (int r=0;r<4;r++){
      int o = m0 + mt*16 + kq*4 + r;
      if (o >= 208) continue;
      #pragma unroll
      for (int nt=0;nt<2;nt++){
        int c = nt*16 + m16;
        dst[(size_t)o*64 + c] = (o < IS) ? f2hb(acc[i][nt][r]) : (unsigned short)0;
      }
    }
  }
}

// ---- k4 v9 (R15, MFMA): fused spatial chain per (b, 64-p tile).
// chain-1 B-fragments read directly from acomb (16B-aligned rows, L1-shared
// across the 4 waves) -- Al LDS staging removed; LDS 36 -> 29 KB.
#define ALS 33    // Sl u32 stride
#define GTS 113   // Gt u32 stride (226 u16)
union K4Sh {
  unsigned int Sl[64*ALS];
  unsigned int Gt[64*GTS];
};
__global__ __launch_bounds__(256,4) void k4_mfma(const void* x, const int* flagp,
    const float* wf, const unsigned short* thph,
    const unsigned short* acomb, const float* g_xs,
    const unsigned int* ws1bf32, unsigned short* x1tp)
{
  __shared__ K4Sh sh;
  __shared__ float ash[64];
  int flag = *flagp;
  int t = threadIdx.x;
  int pt = blockIdx.x % 13, b = blockIdx.x / 13;
  int p0 = pt*64;
  int lane = t & 63, w = t >> 6;
  int col = lane & 15, kq = lane >> 4;

  // Sl[p][c-pair]: paired u32 loads from thph (2 p's per unit)
  const unsigned short* tb = thph + (size_t)b*64*HW;
  for (int i=t; i<32*32; i+=256){
    int c2 = i>>5, q = i&31;
    int p = p0 + 2*q;
    unsigned int w0 = 0u, w1 = 0u;
    if (p < HW){                    // p even, HW even -> p+1 < HW
      int c = 2*c2;
      unsigned int a0 = *(const unsigned int*)(tb + (size_t)c*HW + p);
      unsigned int a1 = *(const unsigned int*)(tb + (size_t)(c+1)*HW + p);
      w0 = (a0 & 0xffffu) | (a1 << 16);
      w1 = (a0 >> 16) | (a1 & 0xffff0000u);
    }
    sh.Sl[(2*q+0)*ALS + c2] = w0;
    sh.Sl[(2*q+1)*ALS + c2] = w1;
  }
  __syncthreads();

  const unsigned short* Ab16 = acomb + (size_t)b*208*64 + (size_t)col*64 + kq*8;
  fragf4 acc1[13];
  #pragma unroll
  for (int nt=0; nt<13; nt++)
    #pragma unroll
    for (int r=0;r<4;r++) acc1[nt][r] = 0.f;
  #pragma unroll
  for (int kk=0; kk<2; kk++){
    FragU af;
    #pragma unroll
    for (int q=0;q<4;q++) af.w[q] = sh.Sl[(w*16+col)*ALS + kk*16 + kq*4 + q];
    #pragma unroll
    for (int nt=0; nt<13; nt++){
      short8 bf8 = *(const short8*)(Ab16 + (size_t)nt*16*64 + kk*32);
      acc1[nt] = __builtin_amdgcn_mfma_f32_16x16x32_bf16(af.s8, bf8, acc1[nt], 0,0,0);
    }
  }
  __syncthreads();   // Sl dead; Gt aliases it

  unsigned short* Gt16 = (unsigned short*)sh.Gt;
  for (int i=t; i<64*9; i+=256){
    int pp = i/9, q = i - pp*9;
    sh.Gt[pp*GTS + 104 + q] = 0u;
  }
  if (t < 64){
    int p = p0 + t;
    float gx = (p < HW) ? g_xs[b*HW + p] : 0.f;
    Gt16[t*226 + 0] = f2hb(gx);
  }
  #pragma unroll
  for (int nt=0; nt<13; nt++){
    int o = nt*16 + col;
    float sc = wf[O_GGSS + o], shf = wf[O_GGSB + o];
    #pragma unroll
    for (int r=0;r<4;r++){
      int pp = w*16 + kq*4 + r;
      float g = fmaxf(sc*acc1[nt][r] + shf, 0.f);
      Gt16[pp*226 + 1 + o] = f2hb(g);
    }
  }
  __syncthreads();

  fragf4 acc2[4];
  #pragma unroll
  for (int nt=0; nt<4; nt++)
    #pragma unroll
    for (int r=0;r<4;r++) acc2[nt][r] = 0.f;
  #pragma unroll
  for (int kk=0; kk<7; kk++){
    FragU af;
    #pragma unroll
    for (int q=0;q<4;q++) af.w[q] = sh.Gt[(w*16+col)*GTS + kk*16 + kq*4 + q];
    #pragma unroll
    for (int nt=0; nt<4; nt++){
      FragU bf;
      #pragma unroll
      for (int q=0;q<4;q++) bf.w[q] = ws1bf32[(nt*16+col)*112 + kk*16 + kq*4 + q];
      acc2[nt] = __builtin_amdgcn_mfma_f32_16x16x32_bf16(af.s8, bf.s8, acc2[nt], 0,0,0);
    }
  }

  float wys[4] = {0.f,0.f,0.f,0.f};
  #pragma unroll
  for (int nt=0; nt<4; nt++){
    int o2 = nt*16 + col;
    bool vd = (o2 < DS);
    float s1 = vd ? wf[O_WS1S+o2] : 0.f;
    float b1 = vd ? wf[O_WS1B+o2] : 0.f;
    float w2 = vd ? wf[O_WS2W+o2] : 0.f;
    #pragma unroll
    for (int r=0;r<4;r++){
      float z = fmaxf(s1*acc2[nt][r] + b1, 0.f);
      wys[r] += w2*z;
    }
  }
  #pragma unroll
  for (int m=1; m<16; m<<=1){
    #pragma unroll
    for (int r=0;r<4;r++) wys[r] += __shfl_xor(wys[r], m, 16);
  }
  if (col == 0){
    float s2 = wf[O_WS2S], b2 = wf[O_WS2B];
    #pragma unroll
    for (int r=0;r<4;r++){
      int pp = w*16 + kq*4 + r;
      ash[pp] = sigf(s2*wys[r] + b2);
    }
  }
  __syncthreads();

  // x1 epilogue, 4-wide (p = p0 + q*4; p<HW <=> p+4<=HW since p%4==0, HW%4==0)
  for (int i=t; i<CC*16; i+=256){
    int c = i>>4, q = i&15;
    int p = p0 + q*4;
    if (p < HW){
      float a0 = ash[q*4+0], a1 = ash[q*4+1], a2 = ash[q*4+2], a3 = ash[q*4+3];
      size_t base = (size_t)b*CC*HW + (size_t)c*HW + p;
      float v0,v1,v2,v3;
      if (flag){
        uint2 u = *(const uint2*)((const unsigned short*)x + base);
        v0 = a0*hb2f((unsigned short)(u.x & 0xffff));
        v1 = a1*hb2f((unsigned short)(u.x >> 16));
        v2 = a2*hb2f((unsigned short)(u.y & 0xffff));
        v3 = a3*hb2f((unsigned short)(u.y >> 16));
      } else {
        float4 xv = *(const float4*)((const float*)x + base);
        v0 = a0*xv.x; v1 = a1*xv.y; v2 = a2*xv.z; v3 = a3*xv.w;
      }
      uint2 o2;
      o2.x = (unsigned)f2hb(v0) | ((unsigned)f2hb(v1)<<16);
      o2.y = (unsigned)f2hb(v2) | ((unsigned)f2hb(v3)<<16);
      *(uint2*)(x1tp + base) = o2;
    }
  }
}

// ---- k8 v4 (R15, MFMA): out[g,c] = relu(sc*(sum_p Wall[g,p]*x1[b,p,c])+sh),
// g in [0,588). LDS/barrier-free: A/B fragments loaded straight from global
// (16B-aligned; A L1-shared across waves; B read-once). Garbage A rows >= 588
// only touch discarded output rows (finite bf16, in-bounds wggs region).
__global__ __launch_bounds__(256) void k8_mfma(const unsigned short* wbf,
    const unsigned short* x1tp, const float* wf, float* outp)
{
  int t = threadIdx.x;
  int j = blockIdx.x & 63;
  int b = (j&7)*8 + (j>>3);
  int mt = blockIdx.x >> 6;          // 0..12
  int m0 = mt*48;
  int lane = t & 63, w = t >> 6;
  int m16 = lane & 15, kq = lane >> 4;
  const unsigned short* arow = wbf + (size_t)(m0 + m16)*HW + kq*8;
  const unsigned short* brow = x1tp + (size_t)b*CC*HW + (size_t)(w*32 + m16)*HW + kq*8;
  short8 zz = zero8();
  fragf4 acc[3][2];
  #pragma unroll
  for (int st=0; st<3; st++)
    #pragma unroll
    for (int ct=0; ct<2; ct++)
      #pragma unroll
      for (int r=0; r<4; r++) acc[st][ct][r] = 0.f;

  for (int kk=0; kk<25; kk++){
    int p = kk*32 + kq*8;
    bool ok = (p + 8 <= HW);
    short8 af[3], bfr[2];
    #pragma unroll
    for (int st=0; st<3; st++)
      af[st] = ok ? *(const short8*)(arow + (size_t)st*16*HW + kk*32) : zz;
    #pragma unroll
    for (int ct=0; ct<2; ct++)
      bfr[ct] = ok ? *(const short8*)(brow + (size_t)ct*16*HW + kk*32) : zz;
    #pragma unroll
    for (int st=0; st<3; st++){
      acc[st][0] = __builtin_amdgcn_mfma_f32_16x16x32_bf16(af[st], bfr[0], acc[st][0], 0,0,0);
      acc[st][1] = __builtin_amdgcn_mfma_f32_16x16x32_bf16(af[st], bfr[1], acc[st][1], 0,0,0);
    }
  }
  #pragma unroll
  for (int st=0; st<3; st++){
    #pragma unroll
    for (int r=0; r<4; r++){
      int g = m0 + st*16 + kq*4 + r;
      if (g >= 3*IS) continue;
      int which = (g >= 2*IS) ? 2 : (g >= IS ? 1 : 0);
      int s = g - which*IS;
      int so = (which==2) ? O_GXCS : O_THCS + which*392;
      float sc = wf[so + s], sh = wf[so + 196 + s];
      float* dst = outp + (size_t)which*(64*IS*CC) + ((size_t)b*IS + s)*CC;
      #pragma unroll
      for (int ct=0; ct<2; ct++){
        int c = (w*2+ct)*16 + m16;
        dst[c] = fmaxf(sc*acc[st][ct][r] + sh, 0.f);
      }
    }
  }
}

// ---- k9 v2 (R12): Bph[b,s,o]=sum_j ggc_w[o,j]*phc[b,s,j]; Bth with thc.
__global__ __launch_bounds__(256) void k9_bfact(const float* wf, const float* thcp,
    const float* phcp, float* Bph, float* Bth)
{
  __shared__ __align__(16) float wtl[32*32*4];   // 16 KB
  int t = threadIdx.x;
  int sq = blockIdx.x & 3;
  int b  = (blockIdx.x >> 2) & 63;
  int which = blockIdx.x >> 8;
  for (int i = t; i < 32*32; i += 256){
    int jc = i >> 5, o = i & 31;
    *(float4*)(wtl + i*4) =
        *(const float4*)(wf + O_GGCW + o*256 + which*CC + jc*4);
  }
  __syncthreads();
  const float* src = which ? thcp : phcp;
  float* dst = which ? Bth : Bph;
  int o = t & 31, sloc = t >> 5;
  int s0 = sq*49;
  float acc[7];
  #pragma unroll
  for (int k=0;k<7;k++) acc[k]=0.f;
  const float* srow[7];
  #pragma unroll
  for (int k=0;k<7;k++){
    int sl = sloc + 8*k;
    srow[k] = src + ((size_t)b*IS + s0 + (sl<49 ? sl : 0))*CC;
  }
  for (int jc=0; jc<32; jc++){
    float4 wv = *(const float4*)(wtl + (jc*32+o)*4);
    #pragma unroll
    for (int k=0;k<7;k++){
      if (sloc + 8*k < 49){
        float4 sv = *(const float4*)(srow[k] + jc*4);
        acc[k] += wv.x*sv.x + wv.y*sv.y + wv.z*sv.z + wv.w*sv.w;
      }
    }
  }
  #pragma unroll
  for (int k=0;k<7;k++){
    int sl = sloc + 8*k;
    if (sl < 49){
      dst[((size_t)b*IS + s0 + sl)*IC + o] = acc[k];
    }
  }
}

// ---- k10a: s-chunk partial accumulation. Grid (b x 14 chunks), thread (d, o-half).
__global__ __launch_bounds__(256) void k10a_part(const float* thcp, const float* phcp,
    const float* gxcp, const float* Bph, const float* Bth,
    float* part, float* gxp)
{
  int t = threadIdx.x;
  int d = t & 127, oh = t >> 7;
  int sc = blockIdx.x % 14, b = blockIdx.x / 14;
  int s0 = sc*14;
  float acc[16];
  #pragma unroll
  for (int o=0;o<16;o++) acc[o]=0.f;
  float gxa = 0.f;
  for (int i=0;i<14;i++){
    int s = s0 + i;
    size_t base = ((size_t)b*IS + s)*CC + d;
    float tv = thcp[base], pv = phcp[base];
    if (oh == 0) gxa += gxcp[base];
    const float* bp = Bph + ((size_t)b*IS + s)*IC + oh*16;
    const float* bt = Bth + ((size_t)b*IS + s)*IC + oh*16;
    #pragma unroll
    for (int o=0;o<16;o++) acc[o] += bp[o]*tv + bt[o]*pv;
  }
  float* pb = part + (((size_t)b*14 + sc)*IC + oh*16)*CC + d;
  #pragma unroll
  for (int o=0;o<16;o++) pb[(size_t)o*CC] = acc[o];
  if (oh == 0) gxp[((size_t)b*14 + sc)*CC + d] = gxa;
}

// ---- k10b: reduce 14 chunks + wc1/wc2/sigmoid epilogue -> c_att[b,d]
__global__ void k10b_catt(const float* wf, const float* part, const float* gxp,
                          float* c_att)
{
  int idx = blockIdx.x*256 + threadIdx.x;    // 64*128 exact
  int d = idx & 127;
  int b = idx >> 7;
  float acc[IC];
  #pragma unroll
  for (int o=0;o<IC;o++) acc[o]=0.f;
  float gx = 0.f;
  for (int sc=0; sc<14; sc++){
    gx += gxp[((size_t)b*14 + sc)*CC + d];
    const float* pb = part + ((size_t)b*14 + sc)*IC*CC + d;
    #pragma unroll
    for (int o=0;o<IC;o++) acc[o] += pb[(size_t)o*CC];
  }
  gx *= (1.f/196.f);
  #pragma unroll
  for (int o=0;o<IC;o++) acc[o] = fmaxf(wf[O_GGCS+o]*acc[o]+wf[O_GGCB+o], 0.f);
  float acc2 = 0.f;
  #pragma unroll
  for (int o2=0;o2<8;o2++){
    float tt = wf[O_WC1W + o2*33]*gx;
    #pragma unroll
    for (int o=0;o<IC;o++) tt += wf[O_WC1W + o2*33+1+o]*acc[o];
    float z = fmaxf(wf[O_WC1S+o2]*tt + wf[O_WC1B+o2], 0.f);
    acc2 += wf[O_WC2W+o2]*z;
  }
  c_att[idx] = sigf(wf[O_WC2S]*acc2 + wf[O_WC2B]);
}

// ---- k12 v2: out[b,c,p] = c_att[b,c]*x1tp[b,c,p] — pure streaming
__global__ void k12_final(const int* flagp, const unsigned int* x1tp2,
                          const float* c_att, void* out)
{
  int i = blockIdx.x*256 + threadIdx.x;      // over BB*CC*HW/2 uints, exact
  int flag = *flagp;
  unsigned int v = x1tp2[i];
  float a = c_att[i/392];                    // 392 uints per (b,c) row
  float v0 = a*hb2f((unsigned short)(v & 0xffff));
  float v1 = a*hb2f((unsigned short)(v >> 16));
  if (flag){
    ((unsigned int*)out)[i] = (unsigned)f2hb(v0) | ((unsigned)f2hb(v1)<<16);
  } else {
    ((float*)out)[2*i+0] = v0;
    ((float*)out)[2*i+1] = v1;
  }
}

extern "C" void kernel_launch(void* const* d_in, const int* in_sizes, int n_in,
                              void* d_out, int out_size, void* d_ws, size_t ws_size,
                              hipStream_t stream)
{
  const void* x = d_in[0];

  float* W = (float*)d_ws;
  int*   flag  = (int*)W;                    // W[0..63] reserved
  float* wf    = W + 64;                     // 800768
  float* theta = wf + WF_TOTAL;              // 1605632 (scratch; part alias)
  unsigned short* thph = (unsigned short*)(theta + 1605632); // 3211264 u16 (old phi slot)
  float* g_xs  = theta + 2*1605632;          // 50176
  float* Aphi  = g_xs + 50176;               // 401408 (acomb lives here)
  float* Atheta= Aphi + 401408;              // 401408
  unsigned short* acomb = (unsigned short*)Aphi;  // 64*208*64 u16 = 851968 (fits 802816 f32 x2)
  unsigned short* x1tp = (unsigned short*)(Atheta + 401408); // 6422528 u16 = 3211264 f32 slots
  float* thcp  = Atheta + 401408 + 3211264;  // 1605632
  float* phcp  = thcp + 1605632;             // 1605632
  float* gxcp  = phcp + 1605632;             // 1605632 (thcp/phcp/gxcp contiguous!)
  float* Bph   = gxcp + 1605632;             // 401408
  float* Bth   = Bph + 401408;               // 401408
  unsigned int* ws1bf32 = (unsigned int*)(Bth + 401408);  // 7168 u32 (slot 9664)
  float* c_att = (float*)(ws1bf32) + 9664;   // 8192
  unsigned short* wbf = (unsigned short*)(c_att + 8192);  // 780608 u16 (~53.9 MiB total)
  unsigned short* wggs = wbf + 3*IS*HW;      // 2*196*784 u16
  unsigned short* wthph = wbf + 5*IS*HW;     // 96*128 u16 (tail of wbf)
  // k10 partials reuse dead theta..Atheta region (4,064,256 contiguous floats):
  float* part = theta;                       // 64*14*32*128 = 3,670,016
  float* gxp  = theta + 3670016;             // 64*14*128  = 114,688 (fits: 3,784,704 < 4,064,256)

  ConvArgs ca;
  ca.cum[0] = 0;
  for (int i=0;i<36;i++){
    ca.p[i] = d_in[i+1];
    ca.cum[i+1] = ca.cum[i] + SRC_SIZES[i];
    ca.dst[i] = DST_OFF[i];
  }

  kd_detect<<<1, 256, 0, stream>>>(x, flag);
  kc_convert<<<(800716+255)/256, 256, 0, stream>>>(ca, flag, wf);
  kw_wbf<<<(KW_TOT+255)/256, 256, 0, stream>>>(wf, wbf);
  k0_ws1bf<<<(64*112+255)/256, 256, 0, stream>>>(wf, ws1bf32);
  k1k2_mfma<<<64*13, 256, 0, stream>>>(x, flag, wf, wthph, thph, g_xs);
  k3_mfma<<<2*64*2, 256, 0, stream>>>(wggs, thph, acomb);
  k4_mfma<<<64*13, 256, 0, stream>>>(x, flag, wf, thph, acomb,
      g_xs, ws1bf32, x1tp);
  k8_mfma<<<13*64, 256, 0, stream>>>(wbf, x1tp, wf, thcp);
  k9_bfact<<<2*64*4, 256, 0, stream>>>(wf, thcp, phcp, Bph, Bth);
  k10a_part<<<64*14, 256, 0, stream>>>(thcp, phcp, gxcp, Bph, Bth, part, gxp);
  k10b_catt<<<(BB*CC)/256, 256, 0, stream>>>(wf, part, gxp, c_att);
  k12_final<<<(BB*CC*HW/2)/256, 256, 0, stream>>>(flag, (const unsigned int*)x1tp,
      c_att, d_out);
}

// Round 8
// 332.904 us; speedup vs baseline: 1.0232x; 1.0232x over previous
//
#include <hip/hip_runtime.h>
#include <hip/hip_bf16.h>
#include <math.h>

// RGA module: B=64, C=128, HW=784, IC=32, IS=196, DS=49, DC=8.
// Rank-32 factorization removes Gs [b,784,784] and Gc [b,128,128] entirely.
// R5: k8 on MFMA. R7: k4 spatial chain fully on MFMA.
// R8: k10 split into s-chunk partials (896 blocks) + reduce.
// R9: k1+k2 fused into one LDS-tiled f32 GEMM.
// R10: k3 ported to the k8 MFMA template; theta/phi stored bf16 (thph).
// R11: k8 re-gridded (3 'which' GEMMs merged, 832 blocks, XCD-swizzled b).
// R12: k9 rebuilt (LDS-transposed weights, 60.5us -> ~8us).
// R13: k1k2 ported to MFMA (45us -> ~12us).
// R14: k4 staging de-scalarized via acomb (k3 emits k4's Al layout).
// R15 (REVERTED): LDS/barrier-free k8+k4 regressed 333->341us -- per-wave
//      direct loads lost block-wide staging MLP at ~3 blocks/CU.
// R16: revert to R14 k4/k8; merge k0 into kw (one fewer launch); k12
//      vectorized to uint4 (392 u32/row % 4 == 0 -> row-pure vectors,
//      12544->3136 blocks, 1/4 VMEM insts). Bit-identical numerics.

#define BB 64
#define CC 128
#define HW 784
#define IC 32
#define IS 196
#define DS 49

// ---- wf (converted f32 inputs) offsets, padded to 4-float alignment ----
#define O_THW 0
#define O_PHW 4096
#define O_GGSW 8192
#define O_GXSW 315520
#define O_WS1W 319616
#define O_WS2W 329272
#define O_THCW 329324
#define O_PHCW 482988
#define O_GGCW 636652
#define O_GXCW 644844
#define O_WC1W 798508
#define O_WC2W 798772
#define O_THS 798780
#define O_THB 798812
#define O_PHS 798844
#define O_PHB 798876
#define O_GGSS 798908
#define O_GGSB 799104
#define O_GXSS 799300
#define O_GXSB 799332
#define O_WS1S 799364
#define O_WS1B 799416
#define O_WS2S 799468
#define O_WS2B 799472
#define O_THCS 799476
#define O_THCB 799672
#define O_PHCS 799868
#define O_PHCB 800064
#define O_GGCS 800260
#define O_GGCB 800292
#define O_GXCS 800324
#define O_GXCB 800520
#define O_WC1S 800716
#define O_WC1B 800724
#define O_WC2S 800732
#define O_WC2B 800736
#define WF_TOTAL 800768

static const int SRC_SIZES[36] = {
  4096,4096,307328,4096,9653,49,153664,153664,8192,153664,264,8,
  32,32,32,32,196,196,32,32,49,49,1,1,196,196,196,196,32,32,196,196,8,8,1,1};
static const int DST_OFF[36] = {
  O_THW,O_PHW,O_GGSW,O_GXSW,O_WS1W,O_WS2W,O_THCW,O_PHCW,O_GGCW,O_GXCW,O_WC1W,O_WC2W,
  O_THS,O_THB,O_PHS,O_PHB,O_GGSS,O_GGSB,O_GXSS,O_GXSB,O_WS1S,O_WS1B,O_WS2S,O_WS2B,
  O_THCS,O_THCB,O_PHCS,O_PHCB,O_GGCS,O_GGCB,O_GXCS,O_GXCB,O_WC1S,O_WC1B,O_WC2S,O_WC2B};

struct ConvArgs { const void* p[36]; int cum[37]; int dst[36]; };

typedef __attribute__((ext_vector_type(8))) short short8;   // 8 bf16 (4 VGPRs)
typedef __attribute__((ext_vector_type(4))) float fragf4;   // MFMA C/D

union FragU { unsigned int w[4]; short8 s8; };

__device__ __forceinline__ float sigf(float v){ return 1.0f/(1.0f+expf(-v)); }
__device__ __forceinline__ float hb2f(unsigned short h){ return __uint_as_float(((unsigned)h)<<16); }
__device__ __forceinline__ unsigned short f2hb(float v){
  __hip_bfloat16 hb = __float2bfloat16(v);
  return *reinterpret_cast<unsigned short*>(&hb);
}
__device__ __forceinline__ float loadx(const void* x, int flag, size_t idx){
  if (flag) return hb2f(((const unsigned short*)x)[idx]);
  return ((const float*)x)[idx];
}

// ---- kd: dtype probe. bf16 data -> ~all sane exponents; f32-misread -> ~62%.
__global__ void kd_detect(const void* x, int* flag){
  __shared__ int cnt[256];
  int t = threadIdx.x;
  const unsigned short* h = (const unsigned short*)x;
  int c = 0;
  for (int k=0;k<4;k++){
    unsigned short v = h[t*4+k];
    int e = (v>>7)&0xFF;
    c += (e==0 || (e>=97 && e<=157)) ? 1 : 0;
  }
  cnt[t] = c;
  __syncthreads();
  for (int s=128; s; s>>=1){ if (t<s) cnt[t]+=cnt[t+s]; __syncthreads(); }
  if (t==0) *flag = (cnt[0] >= 973) ? 1 : 0;
}

// ---- kc: convert all non-x inputs to f32 arena wf
__global__ void kc_convert(ConvArgs a, const int* flagp, float* wf){
  int flag = *flagp;
  int g = blockIdx.x*256 + threadIdx.x;
  if (g >= a.cum[36]) return;
  int i = 0;
  while (g >= a.cum[i+1]) i++;
  int local = g - a.cum[i];
  float v;
  if (flag) v = hb2f(((const unsigned short*)a.p[i])[local]);
  else      v = ((const float*)a.p[i])[local];
  wf[a.dst[i] + local] = v;
}

// ---- kw (R16: +k0 merged): bf16 weight copies + ws1bf u32 packing
#define KW_TOT (5*IS*HW + 96*CC)
#define KWK0_TOT (KW_TOT + 64*112)
__global__ void kw_wbf(const float* wf, unsigned short* wbf, unsigned int* ws1bf32){
  int i = blockIdx.x*256 + threadIdx.x;
  if (i >= KWK0_TOT) return;
  if (i < KW_TOT){
    float v;
    if (i < 3*IS*HW){
      int which = i/(IS*HW), r = i - which*(IS*HW);
      int off = which==0?O_THCW:(which==1?O_PHCW:O_GXCW);
      v = wf[off + r];
    } else if (i < 5*IS*HW){
      int which = i/(IS*HW), r = i - which*(IS*HW);
      int row = r/HW, col = r - row*HW;
      v = wf[O_GGSW + row*(2*HW) + (which-3)*HW + col];
    } else {
      int r = i - 5*IS*HW;               // 0..12287
      int row = r >> 7, col = r & 127;   // th 0-31, ph 32-63, gxs 64-95
      v = (row < 64) ? wf[row*CC + col] : wf[O_GXSW + (row-64)*CC + col];
    }
    wbf[i] = f2hb(v);
  } else {
    int j = i - KW_TOT;                  // 0..7167: ws1bf [64][112] u32
    int o2 = j/112, k2 = j - o2*112;
    int k = k2*2;
    float v0 = (o2<DS && k<197)   ? wf[O_WS1W + o2*197 + k]   : 0.f;
    float v1 = (o2<DS && k+1<197) ? wf[O_WS1W + o2*197 + k+1] : 0.f;
    ws1bf32[j] = (unsigned)f2hb(v0) | ((unsigned)f2hb(v1)<<16);
  }
}

// ---- k1k2 v3 (R13, MFMA): theta/phi/g_xs projections.
#define XST 68   // Xl u32 stride per p-row (272B: 16B-aligned b128 reads)
__global__ __launch_bounds__(256) void k1k2_mfma(const void* x, const int* flagp,
    const float* wf, const unsigned short* wthph, unsigned short* thph, float* g_xs)
{
  __shared__ __align__(16) unsigned int Xl[64*XST];   // 17.4 KB
  int flag = *flagp;
  int t = threadIdx.x;
  int pt = blockIdx.x % 13, b = blockIdx.x / 13;
  int p0 = pt*64;

  // stage x^T tile: Xl[p][c] bf16 via 2x2 transpose micro-tiles (8 units/thread)
  #pragma unroll
  for (int k=0; k<8; k++){
    int idx = k*256 + t;
    int q = idx & 31;              // p-pair (coalesced across lanes)
    int c2 = idx >> 5;             // c-pair, 0..63
    int p = p0 + 2*q, c = 2*c2;
    unsigned int w0 = 0u, w1 = 0u;
    if (p < HW){                   // HW even, p even -> p+1 < HW too
      if (flag){
        const unsigned short* xb = (const unsigned short*)x + (size_t)b*CC*HW;
        unsigned int a0 = *(const unsigned int*)(xb + (size_t)c*HW + p);
        unsigned int a1 = *(const unsigned int*)(xb + (size_t)(c+1)*HW + p);
        w0 = (a0 & 0xffffu) | (a1 << 16);
        w1 = (a0 >> 16) | (a1 & 0xffff0000u);
      } else {
        const float* xb = (const float*)x + (size_t)b*CC*HW;
        float2 a0 = *(const float2*)(xb + (size_t)c*HW + p);
        float2 a1 = *(const float2*)(xb + (size_t)(c+1)*HW + p);
        w0 = (unsigned)f2hb(a0.x) | ((unsigned)f2hb(a1.x)<<16);
        w1 = (unsigned)f2hb(a0.y) | ((unsigned)f2hb(a1.y)<<16);
      }
    }
    Xl[(2*q+0)*XST + c2] = w0;
    Xl[(2*q+1)*XST + c2] = w1;
  }
  __syncthreads();

  int lane = t & 63, w = t >> 6;
  int m16 = lane & 15, kq = lane >> 4;
  fragf4 acc[6];
  #pragma unroll
  for (int mt=0; mt<6; mt++)
    #pragma unroll
    for (int r=0;r<4;r++) acc[mt][r] = 0.f;

  const unsigned short* Xu = (const unsigned short*)Xl;
  #pragma unroll
  for (int kk=0; kk<4; kk++){
    short8 bfr = *(const short8*)(Xu + (w*16+m16)*(2*XST) + kk*32 + kq*8);
    #pragma unroll
    for (int mt=0; mt<6; mt++){
      short8 af = *(const short8*)(wthph + (mt*16+m16)*CC + kk*32 + kq*8);
      acc[mt] = __builtin_amdgcn_mfma_f32_16x16x32_bf16(af, bfr, acc[mt], 0,0,0);
    }
  }

  int p = p0 + w*16 + m16;
  // theta/phi epilogue: o = mt*16 + kq*4 + r in [0,64)
  #pragma unroll
  for (int mt=0; mt<4; mt++){
    #pragma unroll
    for (int r=0;r<4;r++){
      int o = mt*16 + kq*4 + r;
      float sc = (o<32) ? wf[O_THS+o] : wf[O_PHS+o-32];
      float sh = (o<32) ? wf[O_THB+o] : wf[O_PHB+o-32];
      float v = fmaxf(sc*acc[mt][r] + sh, 0.f);
      if (p < HW) thph[((size_t)b*64 + o)*HW + p] = f2hb(v);
    }
  }
  // gxs epilogue: relu'd rows 64..95, mean over o via kq-lane reduce
  float gs = 0.f;
  #pragma unroll
  for (int mt=4; mt<6; mt++){
    #pragma unroll
    for (int r=0;r<4;r++){
      int o = (mt-4)*16 + kq*4 + r;
      gs += fmaxf(wf[O_GXSS+o]*acc[mt][r] + wf[O_GXSB+o], 0.f);
    }
  }
  gs += __shfl_xor(gs, 16);
  gs += __shfl_xor(gs, 32);
  if (kq == 0 && p < HW) g_xs[(size_t)b*HW + p] = gs*(1.f/32.f);
}

// ---- k3 v5 (MFMA): writes acomb[b][208][64] bf16 in k4's Al row layout:
//      row o = [Aphi[o][c=0..31] | Atheta[o][c=0..31]]; pad rows zeroed.
#define K3ST 40
__global__ __launch_bounds__(256) void k3_mfma(const unsigned short* wggs,
    const unsigned short* thph, unsigned short* acomb)
{
  __shared__ __align__(16) unsigned short Al[112*K3ST];
  __shared__ __align__(16) unsigned short Bl[32*K3ST];
  int t = threadIdx.x;
  int mh = blockIdx.x & 1;
  int b  = (blockIdx.x >> 1) & 63;
  int which = blockIdx.x >> 7;
  int m0 = mh*112;
  const unsigned short* wsrc = wggs + (size_t)which*IS*HW;
  const unsigned short* ssrc = thph + ((size_t)b*64 + (which ? 0 : 32))*HW;
  int lane = t & 63, w = t >> 6;
  int m16 = lane & 15, kq = lane >> 4;
  fragf4 acc[2][2];
  #pragma unroll
  for (int i=0;i<2;i++)
    #pragma unroll
    for (int nt=0;nt<2;nt++)
      #pragma unroll
      for (int r=0;r<4;r++) acc[i][nt][r] = 0.f;

  for (int kk=0; kk<25; kk++){
    int p0 = kk*32;
    __syncthreads();
    for (int i=t; i<112*4; i+=256){
      int row = i>>2, q = i&3;
      uint4 v = make_uint4(0u,0u,0u,0u);
      int gr = m0 + row, p = p0 + q*8;
      if (gr < IS && p+8 <= HW)
        v = *(const uint4*)(wsrc + (size_t)gr*HW + p);
      *(uint4*)(Al + row*K3ST + q*8) = v;
    }
    if (t < 128){
      int row = t>>2, q = t&3;
      uint4 v = make_uint4(0u,0u,0u,0u);
      int p = p0 + q*8;
      if (p+8 <= HW)
        v = *(const uint4*)(ssrc + (size_t)row*HW + p);
      *(uint4*)(Bl + row*K3ST + q*8) = v;
    }
    __syncthreads();
    short8 bfr[2];
    #pragma unroll
    for (int nt=0;nt<2;nt++)
      bfr[nt] = *(const short8*)(Bl + (nt*16+m16)*K3ST + kq*8);
    #pragma unroll
    for (int i=0;i<2;i++){
      int mt = w + 4*i;
      if (mt < 7){
        short8 af = *(const short8*)(Al + (mt*16+m16)*K3ST + kq*8);
        acc[i][0] = __builtin_amdgcn_mfma_f32_16x16x32_bf16(af, bfr[0], acc[i][0], 0,0,0);
        acc[i][1] = __builtin_amdgcn_mfma_f32_16x16x32_bf16(af, bfr[1], acc[i][1], 0,0,0);
      }
    }
  }
  unsigned short* dst = acomb + (size_t)b*208*64 + which*32;
  #pragma unroll
  for (int i=0;i<2;i++){
    int mt = w + 4*i;
    if (mt >= 7) continue;
    #pragma unroll
    for (int r=0;r<4;r++){
      int o = m0 + mt*16 + kq*4 + r;
      if (o >= 208) continue;
      #pragma unroll
      for (int nt=0;nt<2;nt++){
        int c = nt*16 + m16;
        dst[(size_t)o*64 + c] = (o < IS) ? f2hb(acc[i][nt][r]) : (unsigned short)0;
      }
    }
  }
}

// ---- k4 v8 (R14, restored): fused spatial chain per (b, 64-p tile).
// Al staged as uint4 copies from acomb (pre-packed bf16); stride 72 u16
// (144B, 16B-aligned b128, 2-way banks = free). Sl staged via paired u32.
#define A4ST 72   // Al16 u16 stride
#define ALS 33    // Sl u32 stride
#define GTS 113   // Gt u32 stride (226 u16)
union K4Sh {
  struct { unsigned short Al16[208*A4ST]; unsigned int Sl[64*ALS]; } s1;
  unsigned int Gt[64*GTS];
};
__global__ __launch_bounds__(256,3) void k4_mfma(const void* x, const int* flagp,
    const float* wf, const unsigned short* thph,
    const unsigned short* acomb, const float* g_xs,
    const unsigned int* ws1bf32, unsigned short* x1tp)
{
  __shared__ K4Sh sh;
  __shared__ float ash[64];
  int flag = *flagp;
  int t = threadIdx.x;
  int pt = blockIdx.x % 13, b = blockIdx.x / 13;
  int p0 = pt*64;
  int lane = t & 63, w = t >> 6;
  int col = lane & 15, kq = lane >> 4;

  // Al: 1664 uint4 copies (rows >= IS zeroed; acomb pad rows also zeroed)
  const unsigned short* Ab16 = acomb + (size_t)b*208*64;
  for (int i=t; i<208*8; i+=256){
    int row = i>>3, q = i&7;
    uint4 v = make_uint4(0u,0u,0u,0u);
    if (row < IS) v = *(const uint4*)(Ab16 + (size_t)row*64 + q*8);
    *(uint4*)(sh.s1.Al16 + (size_t)row*A4ST + q*8) = v;
  }
  // Sl[p][c-pair]: paired u32 loads from thph (2 p's per unit)
  const unsigned short* tb = thph + (size_t)b*64*HW;
  for (int i=t; i<32*32; i+=256){
    int c2 = i>>5, q = i&31;
    int p = p0 + 2*q;
    unsigned int w0 = 0u, w1 = 0u;
    if (p < HW){                    // p even, HW even -> p+1 < HW
      int c = 2*c2;
      unsigned int a0 = *(const unsigned int*)(tb + (size_t)c*HW + p);
      unsigned int a1 = *(const unsigned int*)(tb + (size_t)(c+1)*HW + p);
      w0 = (a0 & 0xffffu) | (a1 << 16);
      w1 = (a0 >> 16) | (a1 & 0xffff0000u);
    }
    sh.s1.Sl[(2*q+0)*ALS + c2] = w0;
    sh.s1.Sl[(2*q+1)*ALS + c2] = w1;
  }
  __syncthreads();

  fragf4 acc1[13];
  #pragma unroll
  for (int nt=0; nt<13; nt++)
    #pragma unroll
    for (int r=0;r<4;r++) acc1[nt][r] = 0.f;
  #pragma unroll
  for (int kk=0; kk<2; kk++){
    FragU af;
    #pragma unroll
    for (int q=0;q<4;q++) af.w[q] = sh.s1.Sl[(w*16+col)*ALS + kk*16 + kq*4 + q];
    #pragma unroll
    for (int nt=0; nt<13; nt++){
      short8 bf8 = *(const short8*)(sh.s1.Al16 + (size_t)(nt*16+col)*A4ST + kk*32 + kq*8);
      acc1[nt] = __builtin_amdgcn_mfma_f32_16x16x32_bf16(af.s8, bf8, acc1[nt], 0,0,0);
    }
  }
  __syncthreads();   // Al/Sl dead; Gt aliases them

  unsigned short* Gt16 = (unsigned short*)sh.Gt;
  for (int i=t; i<64*9; i+=256){
    int pp = i/9, q = i - pp*9;
    sh.Gt[pp*GTS + 104 + q] = 0u;
  }
  if (t < 64){
    int p = p0 + t;
    float gx = (p < HW) ? g_xs[b*HW + p] : 0.f;
    Gt16[t*226 + 0] = f2hb(gx);
  }
  #pragma unroll
  for (int nt=0; nt<13; nt++){
    int o = nt*16 + col;
    float sc = wf[O_GGSS + o], shf = wf[O_GGSB + o];
    #pragma unroll
    for (int r=0;r<4;r++){
      int pp = w*16 + kq*4 + r;
      float g = fmaxf(sc*acc1[nt][r] + shf, 0.f);
      Gt16[pp*226 + 1 + o] = f2hb(g);
    }
  }
  __syncthreads();

  fragf4 acc2[4];
  #pragma unroll
  for (int nt=0; nt<4; nt++)
    #pragma unroll
    for (int r=0;r<4;r++) acc2[nt][r] = 0.f;
  #pragma unroll
  for (int kk=0; kk<7; kk++){
    FragU af;
    #pragma unroll
    for (int q=0;q<4;q++) af.w[q] = sh.Gt[(w*16+col)*GTS + kk*16 + kq*4 + q];
    #pragma unroll
    for (int nt=0; nt<4; nt++){
      FragU bf;
      #pragma unroll
      for (int q=0;q<4;q++) bf.w[q] = ws1bf32[(nt*16+col)*112 + kk*16 + kq*4 + q];
      acc2[nt] = __builtin_amdgcn_mfma_f32_16x16x32_bf16(af.s8, bf.s8, acc2[nt], 0,0,0);
    }
  }

  float wys[4] = {0.f,0.f,0.f,0.f};
  #pragma unroll
  for (int nt=0; nt<4; nt++){
    int o2 = nt*16 + col;
    bool vd = (o2 < DS);
    float s1 = vd ? wf[O_WS1S+o2] : 0.f;
    float b1 = vd ? wf[O_WS1B+o2] : 0.f;
    float w2 = vd ? wf[O_WS2W+o2] : 0.f;
    #pragma unroll
    for (int r=0;r<4;r++){
      float z = fmaxf(s1*acc2[nt][r] + b1, 0.f);
      wys[r] += w2*z;
    }
  }
  #pragma unroll
  for (int m=1; m<16; m<<=1){
    #pragma unroll
    for (int r=0;r<4;r++) wys[r] += __shfl_xor(wys[r], m, 16);
  }
  if (col == 0){
    float s2 = wf[O_WS2S], b2 = wf[O_WS2B];
    #pragma unroll
    for (int r=0;r<4;r++){
      int pp = w*16 + kq*4 + r;
      ash[pp] = sigf(s2*wys[r] + b2);
    }
  }
  __syncthreads();

  // x1 epilogue, 4-wide (p = p0 + q*4; p<HW <=> p+4<=HW since p%4==0, HW%4==0)
  for (int i=t; i<CC*16; i+=256){
    int c = i>>4, q = i&15;
    int p = p0 + q*4;
    if (p < HW){
      float a0 = ash[q*4+0], a1 = ash[q*4+1], a2 = ash[q*4+2], a3 = ash[q*4+3];
      size_t base = (size_t)b*CC*HW + (size_t)c*HW + p;
      float v0,v1,v2,v3;
      if (flag){
        uint2 u = *(const uint2*)((const unsigned short*)x + base);
        v0 = a0*hb2f((unsigned short)(u.x & 0xffff));
        v1 = a1*hb2f((unsigned short)(u.x >> 16));
        v2 = a2*hb2f((unsigned short)(u.y & 0xffff));
        v3 = a3*hb2f((unsigned short)(u.y >> 16));
      } else {
        float4 xv = *(const float4*)((const float*)x + base);
        v0 = a0*xv.x; v1 = a1*xv.y; v2 = a2*xv.z; v3 = a3*xv.w;
      }
      uint2 o2;
      o2.x = (unsigned)f2hb(v0) | ((unsigned)f2hb(v1)<<16);
      o2.y = (unsigned)f2hb(v2) | ((unsigned)f2hb(v3)<<16);
      *(uint2*)(x1tp + base) = o2;
    }
  }
}

// ---- k8 v3 (R11/R14, restored): out[g,c] = relu(sc*(sum_p Wall[g,p]*x1[b,p,c])+sh)
#define KST 40
__global__ __launch_bounds__(256) void k8_mfma(const unsigned short* wbf,
    const unsigned short* x1tp, const float* wf, float* outp)
{
  __shared__ __align__(16) unsigned short Al[48*KST];
  __shared__ __align__(16) unsigned short Bl[128*KST];
  int t = threadIdx.x;
  int j = blockIdx.x & 63;
  int b = (j&7)*8 + (j>>3);
  int mt = blockIdx.x >> 6;          // 0..12
  int m0 = mt*48;
  const unsigned short* xsrc = x1tp + (size_t)b*CC*HW;
  int lane = t & 63, w = t >> 6;
  int m16 = lane & 15, kq = lane >> 4;
  fragf4 acc[3][2];
  #pragma unroll
  for (int st=0; st<3; st++)
    #pragma unroll
    for (int ct=0; ct<2; ct++)
      #pragma unroll
      for (int r=0; r<4; r++) acc[st][ct][r] = 0.f;

  for (int kk=0; kk<25; kk++){
    int p0 = kk*32;
    __syncthreads();
    if (t < 192){
      int row = t>>2, q = t&3;
      uint4 v = make_uint4(0u,0u,0u,0u);
      int g = m0 + row, p = p0 + q*8;
      if (g < 3*IS && p+8 <= HW)
        v = *(const uint4*)(wbf + (size_t)g*HW + p);
      *(uint4*)(Al + row*KST + q*8) = v;
    }
    for (int i=t; i<128*4; i+=256){
      int row = i>>2, q = i&3;
      uint4 v = make_uint4(0u,0u,0u,0u);
      int p = p0 + q*8;
      if (p+8 <= HW)
        v = *(const uint4*)(xsrc + (size_t)row*HW + p);
      *(uint4*)(Bl + row*KST + q*8) = v;
    }
    __syncthreads();
    short8 bfr[2];
    #pragma unroll
    for (int ct=0; ct<2; ct++){
      int n = (w*2+ct)*16 + m16;
      bfr[ct] = *(const short8*)(Bl + n*KST + kq*8);
    }
    #pragma unroll
    for (int st=0; st<3; st++){
      short8 af = *(const short8*)(Al + (st*16+m16)*KST + kq*8);
      acc[st][0] = __builtin_amdgcn_mfma_f32_16x16x32_bf16(af, bfr[0], acc[st][0], 0,0,0);
      acc[st][1] = __builtin_amdgcn_mfma_f32_16x16x32_bf16(af, bfr[1], acc[st][1], 0,0,0);
    }
  }
  #pragma unroll
  for (int st=0; st<3; st++){
    #pragma unroll
    for (int r=0; r<4; r++){
      int g = m0 + st*16 + kq*4 + r;
      if (g >= 3*IS) continue;
      int which = (g >= 2*IS) ? 2 : (g >= IS ? 1 : 0);
      int s = g - which*IS;
      int so = (which==2) ? O_GXCS : O_THCS + which*392;
      float sc = wf[so + s], sh = wf[so + 196 + s];
      float* dst = outp + (size_t)which*(64*IS*CC) + ((size_t)b*IS + s)*CC;
      #pragma unroll
      for (int ct=0; ct<2; ct++){
        int c = (w*2+ct)*16 + m16;
        dst[c] = fmaxf(sc*acc[st][ct][r] + sh, 0.f);
      }
    }
  }
}

// ---- k9 v2 (R12): Bph[b,s,o]=sum_j ggc_w[o,j]*phc[b,s,j]; Bth with thc.
__global__ __launch_bounds__(256) void k9_bfact(const float* wf, const float* thcp,
    const float* phcp, float* Bph, float* Bth)
{
  __shared__ __align__(16) float wtl[32*32*4];   // 16 KB
  int t = threadIdx.x;
  int sq = blockIdx.x & 3;
  int b  = (blockIdx.x >> 2) & 63;
  int which = blockIdx.x >> 8;
  for (int i = t; i < 32*32; i += 256){
    int jc = i >> 5, o = i & 31;
    *(float4*)(wtl + i*4) =
        *(const float4*)(wf + O_GGCW + o*256 + which*CC + jc*4);
  }
  __syncthreads();
  const float* src = which ? thcp : phcp;
  float* dst = which ? Bth : Bph;
  int o = t & 31, sloc = t >> 5;
  int s0 = sq*49;
  float acc[7];
  #pragma unroll
  for (int k=0;k<7;k++) acc[k]=0.f;
  const float* srow[7];
  #pragma unroll
  for (int k=0;k<7;k++){
    int sl = sloc + 8*k;
    srow[k] = src + ((size_t)b*IS + s0 + (sl<49 ? sl : 0))*CC;
  }
  for (int jc=0; jc<32; jc++){
    float4 wv = *(const float4*)(wtl + (jc*32+o)*4);
    #pragma unroll
    for (int k=0;k<7;k++){
      if (sloc + 8*k < 49){
        float4 sv = *(const float4*)(srow[k] + jc*4);
        acc[k] += wv.x*sv.x + wv.y*sv.y + wv.z*sv.z + wv.w*sv.w;
      }
    }
  }
  #pragma unroll
  for (int k=0;k<7;k++){
    int sl = sloc + 8*k;
    if (sl < 49){
      dst[((size_t)b*IS + s0 + sl)*IC + o] = acc[k];
    }
  }
}

// ---- k10a: s-chunk partial accumulation. Grid (b x 14 chunks), thread (d, o-half).
__global__ __launch_bounds__(256) void k10a_part(const float* thcp, const float* phcp,
    const float* gxcp, const float* Bph, const float* Bth,
    float* part, float* gxp)
{
  int t = threadIdx.x;
  int d = t & 127, oh = t >> 7;
  int sc = blockIdx.x % 14, b = blockIdx.x / 14;
  int s0 = sc*14;
  float acc[16];
  #pragma unroll
  for (int o=0;o<16;o++) acc[o]=0.f;
  float gxa = 0.f;
  for (int i=0;i<14;i++){
    int s = s0 + i;
    size_t base = ((size_t)b*IS + s)*CC + d;
    float tv = thcp[base], pv = phcp[base];
    if (oh == 0) gxa += gxcp[base];
    const float* bp = Bph + ((size_t)b*IS + s)*IC + oh*16;
    const float* bt = Bth + ((size_t)b*IS + s)*IC + oh*16;
    #pragma unroll
    for (int o=0;o<16;o++) acc[o] += bp[o]*tv + bt[o]*pv;
  }
  float* pb = part + (((size_t)b*14 + sc)*IC + oh*16)*CC + d;
  #pragma unroll
  for (int o=0;o<16;o++) pb[(size_t)o*CC] = acc[o];
  if (oh == 0) gxp[((size_t)b*14 + sc)*CC + d] = gxa;
}

// ---- k10b: reduce 14 chunks + wc1/wc2/sigmoid epilogue -> c_att[b,d]
__global__ void k10b_catt(const float* wf, const float* part, const float* gxp,
                          float* c_att)
{
  int idx = blockIdx.x*256 + threadIdx.x;    // 64*128 exact
  int d = idx & 127;
  int b = idx >> 7;
  float acc[IC];
  #pragma unroll
  for (int o=0;o<IC;o++) acc[o]=0.f;
  float gx = 0.f;
  for (int sc=0; sc<14; sc++){
    gx += gxp[((size_t)b*14 + sc)*CC + d];
    const float* pb = part + ((size_t)b*14 + sc)*IC*CC + d;
    #pragma unroll
    for (int o=0;o<IC;o++) acc[o] += pb[(size_t)o*CC];
  }
  gx *= (1.f/196.f);
  #pragma unroll
  for (int o=0;o<IC;o++) acc[o] = fmaxf(wf[O_GGCS+o]*acc[o]+wf[O_GGCB+o], 0.f);
  float acc2 = 0.f;
  #pragma unroll
  for (int o2=0;o2<8;o2++){
    float tt = wf[O_WC1W + o2*33]*gx;
    #pragma unroll
    for (int o=0;o<IC;o++) tt += wf[O_WC1W + o2*33+1+o]*acc[o];
    float z = fmaxf(wf[O_WC1S+o2]*tt + wf[O_WC1B+o2], 0.f);
    acc2 += wf[O_WC2W+o2]*z;
  }
  c_att[idx] = sigf(wf[O_WC2S]*acc2 + wf[O_WC2B]);
}

// ---- k12 v3 (R16): out[b,c,p] = c_att[b,c]*x1tp[b,c,p], uint4-vectorized.
// 392 u32/row % 4 == 0 -> each uint4 (8 bf16) lies in one (b,c) row; 98
// uint4s per row. 802816 uint4s / 256 = 3136 blocks (was 12544).
__global__ void k12_final(const int* flagp, const uint4* x1tp4,
                          const float* c_att, void* out)
{
  int i = blockIdx.x*256 + threadIdx.x;      // over 802816 uint4s, exact
  int flag = *flagp;
  uint4 v = x1tp4[i];
  float a = c_att[i/98];
  float f[8];
  f[0] = a*hb2f((unsigned short)(v.x & 0xffff));
  f[1] = a*hb2f((unsigned short)(v.x >> 16));
  f[2] = a*hb2f((unsigned short)(v.y & 0xffff));
  f[3] = a*hb2f((unsigned short)(v.y >> 16));
  f[4] = a*hb2f((unsigned short)(v.z & 0xffff));
  f[5] = a*hb2f((unsigned short)(v.z >> 16));
  f[6] = a*hb2f((unsigned short)(v.w & 0xffff));
  f[7] = a*hb2f((unsigned short)(v.w >> 16));
  if (flag){
    uint4 o;
    o.x = (unsigned)f2hb(f[0]) | ((unsigned)f2hb(f[1])<<16);
    o.y = (unsigned)f2hb(f[2]) | ((unsigned)f2hb(f[3])<<16);
    o.z = (unsigned)f2hb(f[4]) | ((unsigned)f2hb(f[5])<<16);
    o.w = (unsigned)f2hb(f[6]) | ((unsigned)f2hb(f[7])<<16);
    ((uint4*)out)[i] = o;
  } else {
    float4* op = (float4*)out + (size_t)i*2;
    op[0] = make_float4(f[0], f[1], f[2], f[3]);
    op[1] = make_float4(f[4], f[5], f[6], f[7]);
  }
}

extern "C" void kernel_launch(void* const* d_in, const int* in_sizes, int n_in,
                              void* d_out, int out_size, void* d_ws, size_t ws_size,
                              hipStream_t stream)
{
  const void* x = d_in[0];

  float* W = (float*)d_ws;
  int*   flag  = (int*)W;                    // W[0..63] reserved
  float* wf    = W + 64;                     // 800768
  float* theta = wf + WF_TOTAL;              // 1605632 (scratch; part alias)
  unsigned short* thph = (unsigned short*)(theta + 1605632); // 3211264 u16 (old phi slot)
  float* g_xs  = theta + 2*1605632;          // 50176
  float* Aphi  = g_xs + 50176;               // 401408 (acomb lives here)
  float* Atheta= Aphi + 401408;              // 401408
  unsigned short* acomb = (unsigned short*)Aphi;  // 64*208*64 u16 = 851968 (fits 802816 f32 x2)
  unsigned short* x1tp = (unsigned short*)(Atheta + 401408); // 6422528 u16 = 3211264 f32 slots
  float* thcp  = Atheta + 401408 + 3211264;  // 1605632
  float* phcp  = thcp + 1605632;             // 1605632
  float* gxcp  = phcp + 1605632;             // 1605632 (thcp/phcp/gxcp contiguous!)
  float* Bph   = gxcp + 1605632;             // 401408
  float* Bth   = Bph + 401408;               // 401408
  unsigned int* ws1bf32 = (unsigned int*)(Bth + 401408);  // 7168 u32 (slot 9664)
  float* c_att = (float*)(ws1bf32) + 9664;   // 8192
  unsigned short* wbf = (unsigned short*)(c_att + 8192);  // 780608 u16 (~53.9 MiB total)
  unsigned short* wggs = wbf + 3*IS*HW;      // 2*196*784 u16
  unsigned short* wthph = wbf + 5*IS*HW;     // 96*128 u16 (tail of wbf)
  // k10 partials reuse dead theta..Atheta region (4,064,256 contiguous floats):
  float* part = theta;                       // 64*14*32*128 = 3,670,016
  float* gxp  = theta + 3670016;             // 64*14*128  = 114,688 (fits: 3,784,704 < 4,064,256)

  ConvArgs ca;
  ca.cum[0] = 0;
  for (int i=0;i<36;i++){
    ca.p[i] = d_in[i+1];
    ca.cum[i+1] = ca.cum[i] + SRC_SIZES[i];
    ca.dst[i] = DST_OFF[i];
  }

  kd_detect<<<1, 256, 0, stream>>>(x, flag);
  kc_convert<<<(800716+255)/256, 256, 0, stream>>>(ca, flag, wf);
  kw_wbf<<<(KWK0_TOT+255)/256, 256, 0, stream>>>(wf, wbf, ws1bf32);
  k1k2_mfma<<<64*13, 256, 0, stream>>>(x, flag, wf, wthph, thph, g_xs);
  k3_mfma<<<2*64*2, 256, 0, stream>>>(wggs, thph, acomb);
  k4_mfma<<<64*13, 256, 0, stream>>>(x, flag, wf, thph, acomb,
      g_xs, ws1bf32, x1tp);
  k8_mfma<<<13*64, 256, 0, stream>>>(wbf, x1tp, wf, thcp);
  k9_bfact<<<2*64*4, 256, 0, stream>>>(wf, thcp, phcp, Bph, Bth);
  k10a_part<<<64*14, 256, 0, stream>>>(thcp, phcp, gxcp, Bph, Bth, part, gxp);
  k10b_catt<<<(BB*CC)/256, 256, 0, stream>>>(wf, part, gxp, c_att);
  k12_final<<<(BB*CC*HW/8)/256, 256, 0, stream>>>(flag, (const uint4*)x1tp,
      c_att, d_out);
}

// Round 9
// 329.075 us; speedup vs baseline: 1.0351x; 1.0116x over previous
//
#include <hip/hip_runtime.h>
#include <hip/hip_bf16.h>
#include <math.h>

// RGA module: B=64, C=128, HW=784, IC=32, IS=196, DS=49, DC=8.
// Rank-32 factorization removes Gs [b,784,784] and Gc [b,128,128] entirely.
// R5: k8 on MFMA. R7: k4 spatial chain fully on MFMA.
// R8: k10 split into s-chunk partials (896 blocks) + reduce.
// R9: k1+k2 fused into one LDS-tiled f32 GEMM.
// R10: k3 ported to the k8 MFMA template; theta/phi stored bf16 (thph).
// R11: k8 re-gridded (3 'which' GEMMs merged, 832 blocks, XCD-swizzled b).
// R12: k9 rebuilt (LDS-transposed weights, 60.5us -> ~8us).
// R13: k1k2 ported to MFMA (45us -> ~12us).
// R14: k4 staging de-scalarized via acomb (k3 emits k4's Al layout).
// R15 (REVERTED): LDS/barrier-free k8+k4 regressed -- lost staging MLP.
// R16: k0 merged into kw; k12 uint4-vectorized.
// R17: k8 2-phase double-buffer (T3-minimum, m248v2 +10%): barriers 50->26,
//      chunk loads overlap compute (issue at kk, write at kk+1, one barrier).
//      k4 epilogue x-loads issued early (T14): after staging loads (younger
//      in vmcnt order -> staging waits don't drain them), consumed after
//      phase 5 -- x-read hides under chains 1-2. Bit-identical numerics.

#define BB 64
#define CC 128
#define HW 784
#define IC 32
#define IS 196
#define DS 49

// ---- wf (converted f32 inputs) offsets, padded to 4-float alignment ----
#define O_THW 0
#define O_PHW 4096
#define O_GGSW 8192
#define O_GXSW 315520
#define O_WS1W 319616
#define O_WS2W 329272
#define O_THCW 329324
#define O_PHCW 482988
#define O_GGCW 636652
#define O_GXCW 644844
#define O_WC1W 798508
#define O_WC2W 798772
#define O_THS 798780
#define O_THB 798812
#define O_PHS 798844
#define O_PHB 798876
#define O_GGSS 798908
#define O_GGSB 799104
#define O_GXSS 799300
#define O_GXSB 799332
#define O_WS1S 799364
#define O_WS1B 799416
#define O_WS2S 799468
#define O_WS2B 799472
#define O_THCS 799476
#define O_THCB 799672
#define O_PHCS 799868
#define O_PHCB 800064
#define O_GGCS 800260
#define O_GGCB 800292
#define O_GXCS 800324
#define O_GXCB 800520
#define O_WC1S 800716
#define O_WC1B 800724
#define O_WC2S 800732
#define O_WC2B 800736
#define WF_TOTAL 800768

static const int SRC_SIZES[36] = {
  4096,4096,307328,4096,9653,49,153664,153664,8192,153664,264,8,
  32,32,32,32,196,196,32,32,49,49,1,1,196,196,196,196,32,32,196,196,8,8,1,1};
static const int DST_OFF[36] = {
  O_THW,O_PHW,O_GGSW,O_GXSW,O_WS1W,O_WS2W,O_THCW,O_PHCW,O_GGCW,O_GXCW,O_WC1W,O_WC2W,
  O_THS,O_THB,O_PHS,O_PHB,O_GGSS,O_GGSB,O_GXSS,O_GXSB,O_WS1S,O_WS1B,O_WS2S,O_WS2B,
  O_THCS,O_THCB,O_PHCS,O_PHCB,O_GGCS,O_GGCB,O_GXCS,O_GXCB,O_WC1S,O_WC1B,O_WC2S,O_WC2B};

struct ConvArgs { const void* p[36]; int cum[37]; int dst[36]; };

typedef __attribute__((ext_vector_type(8))) short short8;   // 8 bf16 (4 VGPRs)
typedef __attribute__((ext_vector_type(4))) float fragf4;   // MFMA C/D

union FragU { unsigned int w[4]; short8 s8; };

__device__ __forceinline__ float sigf(float v){ return 1.0f/(1.0f+expf(-v)); }
__device__ __forceinline__ float hb2f(unsigned short h){ return __uint_as_float(((unsigned)h)<<16); }
__device__ __forceinline__ unsigned short f2hb(float v){
  __hip_bfloat16 hb = __float2bfloat16(v);
  return *reinterpret_cast<unsigned short*>(&hb);
}
__device__ __forceinline__ float loadx(const void* x, int flag, size_t idx){
  if (flag) return hb2f(((const unsigned short*)x)[idx]);
  return ((const float*)x)[idx];
}

// ---- kd: dtype probe. bf16 data -> ~all sane exponents; f32-misread -> ~62%.
__global__ void kd_detect(const void* x, int* flag){
  __shared__ int cnt[256];
  int t = threadIdx.x;
  const unsigned short* h = (const unsigned short*)x;
  int c = 0;
  for (int k=0;k<4;k++){
    unsigned short v = h[t*4+k];
    int e = (v>>7)&0xFF;
    c += (e==0 || (e>=97 && e<=157)) ? 1 : 0;
  }
  cnt[t] = c;
  __syncthreads();
  for (int s=128; s; s>>=1){ if (t<s) cnt[t]+=cnt[t+s]; __syncthreads(); }
  if (t==0) *flag = (cnt[0] >= 973) ? 1 : 0;
}

// ---- kc: convert all non-x inputs to f32 arena wf
__global__ void kc_convert(ConvArgs a, const int* flagp, float* wf){
  int flag = *flagp;
  int g = blockIdx.x*256 + threadIdx.x;
  if (g >= a.cum[36]) return;
  int i = 0;
  while (g >= a.cum[i+1]) i++;
  int local = g - a.cum[i];
  float v;
  if (flag) v = hb2f(((const unsigned short*)a.p[i])[local]);
  else      v = ((const float*)a.p[i])[local];
  wf[a.dst[i] + local] = v;
}

// ---- kw (R16: +k0 merged): bf16 weight copies + ws1bf u32 packing
#define KW_TOT (5*IS*HW + 96*CC)
#define KWK0_TOT (KW_TOT + 64*112)
__global__ void kw_wbf(const float* wf, unsigned short* wbf, unsigned int* ws1bf32){
  int i = blockIdx.x*256 + threadIdx.x;
  if (i >= KWK0_TOT) return;
  if (i < KW_TOT){
    float v;
    if (i < 3*IS*HW){
      int which = i/(IS*HW), r = i - which*(IS*HW);
      int off = which==0?O_THCW:(which==1?O_PHCW:O_GXCW);
      v = wf[off + r];
    } else if (i < 5*IS*HW){
      int which = i/(IS*HW), r = i - which*(IS*HW);
      int row = r/HW, col = r - row*HW;
      v = wf[O_GGSW + row*(2*HW) + (which-3)*HW + col];
    } else {
      int r = i - 5*IS*HW;               // 0..12287
      int row = r >> 7, col = r & 127;   // th 0-31, ph 32-63, gxs 64-95
      v = (row < 64) ? wf[row*CC + col] : wf[O_GXSW + (row-64)*CC + col];
    }
    wbf[i] = f2hb(v);
  } else {
    int j = i - KW_TOT;                  // 0..7167: ws1bf [64][112] u32
    int o2 = j/112, k2 = j - o2*112;
    int k = k2*2;
    float v0 = (o2<DS && k<197)   ? wf[O_WS1W + o2*197 + k]   : 0.f;
    float v1 = (o2<DS && k+1<197) ? wf[O_WS1W + o2*197 + k+1] : 0.f;
    ws1bf32[j] = (unsigned)f2hb(v0) | ((unsigned)f2hb(v1)<<16);
  }
}

// ---- k1k2 v3 (R13, MFMA): theta/phi/g_xs projections.
#define XST 68   // Xl u32 stride per p-row (272B: 16B-aligned b128 reads)
__global__ __launch_bounds__(256) void k1k2_mfma(const void* x, const int* flagp,
    const float* wf, const unsigned short* wthph, unsigned short* thph, float* g_xs)
{
  __shared__ __align__(16) unsigned int Xl[64*XST];   // 17.4 KB
  int flag = *flagp;
  int t = threadIdx.x;
  int pt = blockIdx.x % 13, b = blockIdx.x / 13;
  int p0 = pt*64;

  // stage x^T tile: Xl[p][c] bf16 via 2x2 transpose micro-tiles (8 units/thread)
  #pragma unroll
  for (int k=0; k<8; k++){
    int idx = k*256 + t;
    int q = idx & 31;              // p-pair (coalesced across lanes)
    int c2 = idx >> 5;             // c-pair, 0..63
    int p = p0 + 2*q, c = 2*c2;
    unsigned int w0 = 0u, w1 = 0u;
    if (p < HW){                   // HW even, p even -> p+1 < HW too
      if (flag){
        const unsigned short* xb = (const unsigned short*)x + (size_t)b*CC*HW;
        unsigned int a0 = *(const unsigned int*)(xb + (size_t)c*HW + p);
        unsigned int a1 = *(const unsigned int*)(xb + (size_t)(c+1)*HW + p);
        w0 = (a0 & 0xffffu) | (a1 << 16);
        w1 = (a0 >> 16) | (a1 & 0xffff0000u);
      } else {
        const float* xb = (const float*)x + (size_t)b*CC*HW;
        float2 a0 = *(const float2*)(xb + (size_t)c*HW + p);
        float2 a1 = *(const float2*)(xb + (size_t)(c+1)*HW + p);
        w0 = (unsigned)f2hb(a0.x) | ((unsigned)f2hb(a1.x)<<16);
        w1 = (unsigned)f2hb(a0.y) | ((unsigned)f2hb(a1.y)<<16);
      }
    }
    Xl[(2*q+0)*XST + c2] = w0;
    Xl[(2*q+1)*XST + c2] = w1;
  }
  __syncthreads();

  int lane = t & 63, w = t >> 6;
  int m16 = lane & 15, kq = lane >> 4;
  fragf4 acc[6];
  #pragma unroll
  for (int mt=0; mt<6; mt++)
    #pragma unroll
    for (int r=0;r<4;r++) acc[mt][r] = 0.f;

  const unsigned short* Xu = (const unsigned short*)Xl;
  #pragma unroll
  for (int kk=0; kk<4; kk++){
    short8 bfr = *(const short8*)(Xu + (w*16+m16)*(2*XST) + kk*32 + kq*8);
    #pragma unroll
    for (int mt=0; mt<6; mt++){
      short8 af = *(const short8*)(wthph + (mt*16+m16)*CC + kk*32 + kq*8);
      acc[mt] = __builtin_amdgcn_mfma_f32_16x16x32_bf16(af, bfr, acc[mt], 0,0,0);
    }
  }

  int p = p0 + w*16 + m16;
  // theta/phi epilogue: o = mt*16 + kq*4 + r in [0,64)
  #pragma unroll
  for (int mt=0; mt<4; mt++){
    #pragma unroll
    for (int r=0;r<4;r++){
      int o = mt*16 + kq*4 + r;
      float sc = (o<32) ? wf[O_THS+o] : wf[O_PHS+o-32];
      float sh = (o<32) ? wf[O_THB+o] : wf[O_PHB+o-32];
      float v = fmaxf(sc*acc[mt][r] + sh, 0.f);
      if (p < HW) thph[((size_t)b*64 + o)*HW + p] = f2hb(v);
    }
  }
  // gxs epilogue: relu'd rows 64..95, mean over o via kq-lane reduce
  float gs = 0.f;
  #pragma unroll
  for (int mt=4; mt<6; mt++){
    #pragma unroll
    for (int r=0;r<4;r++){
      int o = (mt-4)*16 + kq*4 + r;
      gs += fmaxf(wf[O_GXSS+o]*acc[mt][r] + wf[O_GXSB+o], 0.f);
    }
  }
  gs += __shfl_xor(gs, 16);
  gs += __shfl_xor(gs, 32);
  if (kq == 0 && p < HW) g_xs[(size_t)b*HW + p] = gs*(1.f/32.f);
}

// ---- k3 v5 (MFMA): writes acomb[b][208][64] bf16 in k4's Al row layout:
//      row o = [Aphi[o][c=0..31] | Atheta[o][c=0..31]]; pad rows zeroed.
#define K3ST 40
__global__ __launch_bounds__(256) void k3_mfma(const unsigned short* wggs,
    const unsigned short* thph, unsigned short* acomb)
{
  __shared__ __align__(16) unsigned short Al[112*K3ST];
  __shared__ __align__(16) unsigned short Bl[32*K3ST];
  int t = threadIdx.x;
  int mh = blockIdx.x & 1;
  int b  = (blockIdx.x >> 1) & 63;
  int which = blockIdx.x >> 7;
  int m0 = mh*112;
  const unsigned short* wsrc = wggs + (size_t)which*IS*HW;
  const unsigned short* ssrc = thph + ((size_t)b*64 + (which ? 0 : 32))*HW;
  int lane = t & 63, w = t >> 6;
  int m16 = lane & 15, kq = lane >> 4;
  fragf4 acc[2][2];
  #pragma unroll
  for (int i=0;i<2;i++)
    #pragma unroll
    for (int nt=0;nt<2;nt++)
      #pragma unroll
      for (int r=0;r<4;r++) acc[i][nt][r] = 0.f;

  for (int kk=0; kk<25; kk++){
    int p0 = kk*32;
    __syncthreads();
    for (int i=t; i<112*4; i+=256){
      int row = i>>2, q = i&3;
      uint4 v = make_uint4(0u,0u,0u,0u);
      int gr = m0 + row, p = p0 + q*8;
      if (gr < IS && p+8 <= HW)
        v = *(const uint4*)(wsrc + (size_t)gr*HW + p);
      *(uint4*)(Al + row*K3ST + q*8) = v;
    }
    if (t < 128){
      int row = t>>2, q = t&3;
      uint4 v = make_uint4(0u,0u,0u,0u);
      int p = p0 + q*8;
      if (p+8 <= HW)
        v = *(const uint4*)(ssrc + (size_t)row*HW + p);
      *(uint4*)(Bl + row*K3ST + q*8) = v;
    }
    __syncthreads();
    short8 bfr[2];
    #pragma unroll
    for (int nt=0;nt<2;nt++)
      bfr[nt] = *(const short8*)(Bl + (nt*16+m16)*K3ST + kq*8);
    #pragma unroll
    for (int i=0;i<2;i++){
      int mt = w + 4*i;
      if (mt < 7){
        short8 af = *(const short8*)(Al + (mt*16+m16)*K3ST + kq*8);
        acc[i][0] = __builtin_amdgcn_mfma_f32_16x16x32_bf16(af, bfr[0], acc[i][0], 0,0,0);
        acc[i][1] = __builtin_amdgcn_mfma_f32_16x16x32_bf16(af, bfr[1], acc[i][1], 0,0,0);
      }
    }
  }
  unsigned short* dst = acomb + (size_t)b*208*64 + which*32;
  #pragma unroll
  for (int i=0;i<2;i++){
    int mt = w + 4*i;
    if (mt >= 7) continue;
    #pragma unroll
    for (int r=0;r<4;r++){
      int o = m0 + mt*16 + kq*4 + r;
      if (o >= 208) continue;
      #pragma unroll
      for (int nt=0;nt<2;nt++){
        int c = nt*16 + m16;
        dst[(size_t)o*64 + c] = (o < IS) ? f2hb(acc[i][nt][r]) : (unsigned short)0;
      }
    }
  }
}

// ---- k4 v10 (R17): fused spatial chain per (b, 64-p tile).
// R14 staging + T14 early-issue of epilogue x-loads (issued AFTER staging
// loads so staging's vmcnt waits leave them in flight; consumed after
// phase 5 -- x-read completes under chains 1-2).
#define A4ST 72   // Al16 u16 stride
#define ALS 33    // Sl u32 stride
#define GTS 113   // Gt u32 stride (226 u16)
union K4Sh {
  struct { unsigned short Al16[208*A4ST]; unsigned int Sl[64*ALS]; } s1;
  unsigned int Gt[64*GTS];
};
__global__ __launch_bounds__(256,3) void k4_mfma(const void* x, const int* flagp,
    const float* wf, const unsigned short* thph,
    const unsigned short* acomb, const float* g_xs,
    const unsigned int* ws1bf32, unsigned short* x1tp)
{
  __shared__ K4Sh sh;
  __shared__ float ash[64];
  int flag = *flagp;
  int t = threadIdx.x;
  int pt = blockIdx.x % 13, b = blockIdx.x / 13;
  int p0 = pt*64;
  int lane = t & 63, w = t >> 6;
  int col = lane & 15, kq = lane >> 4;

  // Al: 1664 uint4 copies (rows >= IS zeroed; acomb pad rows also zeroed)
  const unsigned short* Ab16 = acomb + (size_t)b*208*64;
  for (int i=t; i<208*8; i+=256){
    int row = i>>3, q = i&7;
    uint4 v = make_uint4(0u,0u,0u,0u);
    if (row < IS) v = *(const uint4*)(Ab16 + (size_t)row*64 + q*8);
    *(uint4*)(sh.s1.Al16 + (size_t)row*A4ST + q*8) = v;
  }
  // Sl[p][c-pair]: paired u32 loads from thph (2 p's per unit)
  const unsigned short* tb = thph + (size_t)b*64*HW;
  for (int i=t; i<32*32; i+=256){
    int c2 = i>>5, q = i&31;
    int p = p0 + 2*q;
    unsigned int w0 = 0u, w1 = 0u;
    if (p < HW){                    // p even, HW even -> p+1 < HW
      int c = 2*c2;
      unsigned int a0 = *(const unsigned int*)(tb + (size_t)c*HW + p);
      unsigned int a1 = *(const unsigned int*)(tb + (size_t)(c+1)*HW + p);
      w0 = (a0 & 0xffffu) | (a1 << 16);
      w1 = (a0 >> 16) | (a1 & 0xffff0000u);
    }
    sh.s1.Sl[(2*q+0)*ALS + c2] = w0;
    sh.s1.Sl[(2*q+1)*ALS + c2] = w1;
  }
  // R17: early-issue epilogue x loads (8 units/thread; clamped addr for tail)
  float4 xf[8]; uint2 xh[8];
  if (flag){
    #pragma unroll
    for (int jj=0; jj<8; jj++){
      int i = jj*256 + t;
      int c = i>>4, q = i&15;
      int p = p0 + q*4;
      size_t base = (size_t)b*CC*HW + (size_t)c*HW + (p < HW ? p : 0);
      xh[jj] = *(const uint2*)((const unsigned short*)x + base);
    }
  } else {
    #pragma unroll
    for (int jj=0; jj<8; jj++){
      int i = jj*256 + t;
      int c = i>>4, q = i&15;
      int p = p0 + q*4;
      size_t base = (size_t)b*CC*HW + (size_t)c*HW + (p < HW ? p : 0);
      xf[jj] = *(const float4*)((const float*)x + base);
    }
  }
  __syncthreads();

  fragf4 acc1[13];
  #pragma unroll
  for (int nt=0; nt<13; nt++)
    #pragma unroll
    for (int r=0;r<4;r++) acc1[nt][r] = 0.f;
  #pragma unroll
  for (int kk=0; kk<2; kk++){
    FragU af;
    #pragma unroll
    for (int q=0;q<4;q++) af.w[q] = sh.s1.Sl[(w*16+col)*ALS + kk*16 + kq*4 + q];
    #pragma unroll
    for (int nt=0; nt<13; nt++){
      short8 bf8 = *(const short8*)(sh.s1.Al16 + (size_t)(nt*16+col)*A4ST + kk*32 + kq*8);
      acc1[nt] = __builtin_amdgcn_mfma_f32_16x16x32_bf16(af.s8, bf8, acc1[nt], 0,0,0);
    }
  }
  __syncthreads();   // Al/Sl dead; Gt aliases them

  unsigned short* Gt16 = (unsigned short*)sh.Gt;
  for (int i=t; i<64*9; i+=256){
    int pp = i/9, q = i - pp*9;
    sh.Gt[pp*GTS + 104 + q] = 0u;
  }
  if (t < 64){
    int p = p0 + t;
    float gx = (p < HW) ? g_xs[b*HW + p] : 0.f;
    Gt16[t*226 + 0] = f2hb(gx);
  }
  #pragma unroll
  for (int nt=0; nt<13; nt++){
    int o = nt*16 + col;
    float sc = wf[O_GGSS + o], shf = wf[O_GGSB + o];
    #pragma unroll
    for (int r=0;r<4;r++){
      int pp = w*16 + kq*4 + r;
      float g = fmaxf(sc*acc1[nt][r] + shf, 0.f);
      Gt16[pp*226 + 1 + o] = f2hb(g);
    }
  }
  __syncthreads();

  fragf4 acc2[4];
  #pragma unroll
  for (int nt=0; nt<4; nt++)
    #pragma unroll
    for (int r=0;r<4;r++) acc2[nt][r] = 0.f;
  #pragma unroll
  for (int kk=0; kk<7; kk++){
    FragU af;
    #pragma unroll
    for (int q=0;q<4;q++) af.w[q] = sh.Gt[(w*16+col)*GTS + kk*16 + kq*4 + q];
    #pragma unroll
    for (int nt=0; nt<4; nt++){
      FragU bf;
      #pragma unroll
      for (int q=0;q<4;q++) bf.w[q] = ws1bf32[(nt*16+col)*112 + kk*16 + kq*4 + q];
      acc2[nt] = __builtin_amdgcn_mfma_f32_16x16x32_bf16(af.s8, bf.s8, acc2[nt], 0,0,0);
    }
  }

  float wys[4] = {0.f,0.f,0.f,0.f};
  #pragma unroll
  for (int nt=0; nt<4; nt++){
    int o2 = nt*16 + col;
    bool vd = (o2 < DS);
    float s1 = vd ? wf[O_WS1S+o2] : 0.f;
    float b1 = vd ? wf[O_WS1B+o2] : 0.f;
    float w2 = vd ? wf[O_WS2W+o2] : 0.f;
    #pragma unroll
    for (int r=0;r<4;r++){
      float z = fmaxf(s1*acc2[nt][r] + b1, 0.f);
      wys[r] += w2*z;
    }
  }
  #pragma unroll
  for (int m=1; m<16; m<<=1){
    #pragma unroll
    for (int r=0;r<4;r++) wys[r] += __shfl_xor(wys[r], m, 16);
  }
  if (col == 0){
    float s2 = wf[O_WS2S], b2 = wf[O_WS2B];
    #pragma unroll
    for (int r=0;r<4;r++){
      int pp = w*16 + kq*4 + r;
      ash[pp] = sigf(s2*wys[r] + b2);
    }
  }
  __syncthreads();

  // x1 epilogue: consume early-issued x regs
  #pragma unroll
  for (int jj=0; jj<8; jj++){
    int i = jj*256 + t;
    int c = i>>4, q = i&15;
    int p = p0 + q*4;
    if (p < HW){
      float a0 = ash[q*4+0], a1 = ash[q*4+1], a2 = ash[q*4+2], a3 = ash[q*4+3];
      size_t base = (size_t)b*CC*HW + (size_t)c*HW + p;
      float v0,v1,v2,v3;
      if (flag){
        uint2 u = xh[jj];
        v0 = a0*hb2f((unsigned short)(u.x & 0xffff));
        v1 = a1*hb2f((unsigned short)(u.x >> 16));
        v2 = a2*hb2f((unsigned short)(u.y & 0xffff));
        v3 = a3*hb2f((unsigned short)(u.y >> 16));
      } else {
        float4 xv = xf[jj];
        v0 = a0*xv.x; v1 = a1*xv.y; v2 = a2*xv.z; v3 = a3*xv.w;
      }
      uint2 o2;
      o2.x = (unsigned)f2hb(v0) | ((unsigned)f2hb(v1)<<16);
      o2.y = (unsigned)f2hb(v2) | ((unsigned)f2hb(v3)<<16);
      *(uint2*)(x1tp + base) = o2;
    }
  }
}

// ---- k8 v5 (R17, MFMA, 2-phase dbuf): out[g,c] = relu(sc*(sum_p W[g,p]*x1[b,p,c])+sh)
// Schedule per chunk: compute(buf[cur]) -> write prefetched regs -> buf[cur^1]
// -> ONE barrier -> issue loads for chunk+2. Barriers 50->26; loads get a
// full compute phase of latency cover. LDS 2x(48+128)x40 u16 = 28.2 KB.
#define KST 40
__global__ __launch_bounds__(256) void k8_mfma(const unsigned short* wbf,
    const unsigned short* x1tp, const float* wf, float* outp)
{
  __shared__ __align__(16) unsigned short Al[2][48*KST];
  __shared__ __align__(16) unsigned short Bl[2][128*KST];
  int t = threadIdx.x;
  int j = blockIdx.x & 63;
  int b = (j&7)*8 + (j>>3);
  int mt = blockIdx.x >> 6;          // 0..12
  int m0 = mt*48;
  const unsigned short* xsrc = x1tp + (size_t)b*CC*HW;
  int lane = t & 63, w = t >> 6;
  int m16 = lane & 15, kq = lane >> 4;
  int ar = t>>2, aq8 = (t&3)*8;
  bool aok = (t < 192) && (m0 + ar < 3*IS);
  const unsigned short* arow = wbf + (size_t)(m0 + ar)*HW + aq8;
  const unsigned short* brow0 = xsrc + (size_t)ar*HW + aq8;        // Bl rows 0-63
  const unsigned short* brow1 = xsrc + (size_t)(ar+64)*HW + aq8;   // Bl rows 64-127

  fragf4 acc[3][2];
  #pragma unroll
  for (int st=0; st<3; st++)
    #pragma unroll
    for (int ct=0; ct<2; ct++)
      #pragma unroll
      for (int r=0; r<4; r++) acc[st][ct][r] = 0.f;

  // prologue: chunk 0 (all p valid) -> buf0; then issue chunk 1
  uint4 va = make_uint4(0u,0u,0u,0u), vb0, vb1;
  if (aok) va = *(const uint4*)(arow);
  vb0 = *(const uint4*)(brow0);
  vb1 = *(const uint4*)(brow1);
  if (t < 192) *(uint4*)(&Al[0][ar*KST + aq8]) = va;
  *(uint4*)(&Bl[0][ar*KST + aq8]) = vb0;
  *(uint4*)(&Bl[0][(ar+64)*KST + aq8]) = vb1;
  __syncthreads();
  va = make_uint4(0u,0u,0u,0u);
  if (aok) va = *(const uint4*)(arow + 32);
  vb0 = *(const uint4*)(brow0 + 32);
  vb1 = *(const uint4*)(brow1 + 32);

  int cur = 0;
  for (int kk=0; kk<25; kk++){
    short8 bfr[2];
    #pragma unroll
    for (int ct=0; ct<2; ct++)
      bfr[ct] = *(const short8*)(&Bl[cur][((w*2+ct)*16+m16)*KST + kq*8]);
    #pragma unroll
    for (int st=0; st<3; st++){
      short8 af = *(const short8*)(&Al[cur][(st*16+m16)*KST + kq*8]);
      acc[st][0] = __builtin_amdgcn_mfma_f32_16x16x32_bf16(af, bfr[0], acc[st][0], 0,0,0);
      acc[st][1] = __builtin_amdgcn_mfma_f32_16x16x32_bf16(af, bfr[1], acc[st][1], 0,0,0);
    }
    if (kk < 24){
      // write chunk kk+1 (prefetched into regs) to the other buffer
      if (t < 192) *(uint4*)(&Al[cur^1][ar*KST + aq8]) = va;
      *(uint4*)(&Bl[cur^1][ar*KST + aq8]) = vb0;
      *(uint4*)(&Bl[cur^1][(ar+64)*KST + aq8]) = vb1;
      __syncthreads();
      if (kk < 23){
        // issue chunk kk+2; chunk 24 is the ragged tail (768+aq8+8<=784 iff aq8<=8)
        int off = (kk+2)*32;
        bool pok = (kk < 22) || ((t&3) < 2);
        va = make_uint4(0u,0u,0u,0u);
        vb0 = make_uint4(0u,0u,0u,0u);
        vb1 = make_uint4(0u,0u,0u,0u);
        if (pok){
          if (aok) va = *(const uint4*)(arow + off);
          vb0 = *(const uint4*)(brow0 + off);
          vb1 = *(const uint4*)(brow1 + off);
        }
      }
      cur ^= 1;
    }
  }
  #pragma unroll
  for (int st=0; st<3; st++){
    #pragma unroll
    for (int r=0; r<4; r++){
      int g = m0 + st*16 + kq*4 + r;
      if (g >= 3*IS) continue;
      int which = (g >= 2*IS) ? 2 : (g >= IS ? 1 : 0);
      int s = g - which*IS;
      int so = (which==2) ? O_GXCS : O_THCS + which*392;
      float sc = wf[so + s], sh = wf[so + 196 + s];
      float* dst = outp + (size_t)which*(64*IS*CC) + ((size_t)b*IS + s)*CC;
      #pragma unroll
      for (int ct=0; ct<2; ct++){
        int c = (w*2+ct)*16 + m16;
        dst[c] = fmaxf(sc*acc[st][ct][r] + sh, 0.f);
      }
    }
  }
}

// ---- k9 v2 (R12): Bph[b,s,o]=sum_j ggc_w[o,j]*phc[b,s,j]; Bth with thc.
__global__ __launch_bounds__(256) void k9_bfact(const float* wf, const float* thcp,
    const float* phcp, float* Bph, float* Bth)
{
  __shared__ __align__(16) float wtl[32*32*4];   // 16 KB
  int t = threadIdx.x;
  int sq = blockIdx.x & 3;
  int b  = (blockIdx.x >> 2) & 63;
  int which = blockIdx.x >> 8;
  for (int i = t; i < 32*32; i += 256){
    int jc = i >> 5, o = i & 31;
    *(float4*)(wtl + i*4) =
        *(const float4*)(wf + O_GGCW + o*256 + which*CC + jc*4);
  }
  __syncthreads();
  const float* src = which ? thcp : phcp;
  float* dst = which ? Bth : Bph;
  int o = t & 31, sloc = t >> 5;
  int s0 = sq*49;
  float acc[7];
  #pragma unroll
  for (int k=0;k<7;k++) acc[k]=0.f;
  const float* srow[7];
  #pragma unroll
  for (int k=0;k<7;k++){
    int sl = sloc + 8*k;
    srow[k] = src + ((size_t)b*IS + s0 + (sl<49 ? sl : 0))*CC;
  }
  for (int jc=0; jc<32; jc++){
    float4 wv = *(const float4*)(wtl + (jc*32+o)*4);
    #pragma unroll
    for (int k=0;k<7;k++){
      if (sloc + 8*k < 49){
        float4 sv = *(const float4*)(srow[k] + jc*4);
        acc[k] += wv.x*sv.x + wv.y*sv.y + wv.z*sv.z + wv.w*sv.w;
      }
    }
  }
  #pragma unroll
  for (int k=0;k<7;k++){
    int sl = sloc + 8*k;
    if (sl < 49){
      dst[((size_t)b*IS + s0 + sl)*IC + o] = acc[k];
    }
  }
}

// ---- k10a: s-chunk partial accumulation. Grid (b x 14 chunks), thread (d, o-half).
__global__ __launch_bounds__(256) void k10a_part(const float* thcp, const float* phcp,
    const float* gxcp, const float* Bph, const float* Bth,
    float* part, float* gxp)
{
  int t = threadIdx.x;
  int d = t & 127, oh = t >> 7;
  int sc = blockIdx.x % 14, b = blockIdx.x / 14;
  int s0 = sc*14;
  float acc[16];
  #pragma unroll
  for (int o=0;o<16;o++) acc[o]=0.f;
  float gxa = 0.f;
  for (int i=0;i<14;i++){
    int s = s0 + i;
    size_t base = ((size_t)b*IS + s)*CC + d;
    float tv = thcp[base], pv = phcp[base];
    if (oh == 0) gxa += gxcp[base];
    const float* bp = Bph + ((size_t)b*IS + s)*IC + oh*16;
    const float* bt = Bth + ((size_t)b*IS + s)*IC + oh*16;
    #pragma unroll
    for (int o=0;o<16;o++) acc[o] += bp[o]*tv + bt[o]*pv;
  }
  float* pb = part + (((size_t)b*14 + sc)*IC + oh*16)*CC + d;
  #pragma unroll
  for (int o=0;o<16;o++) pb[(size_t)o*CC] = acc[o];
  if (oh == 0) gxp[((size_t)b*14 + sc)*CC + d] = gxa;
}

// ---- k10b: reduce 14 chunks + wc1/wc2/sigmoid epilogue -> c_att[b,d]
__global__ void k10b_catt(const float* wf, const float* part, const float* gxp,
                          float* c_att)
{
  int idx = blockIdx.x*256 + threadIdx.x;    // 64*128 exact
  int d = idx & 127;
  int b = idx >> 7;
  float acc[IC];
  #pragma unroll
  for (int o=0;o<IC;o++) acc[o]=0.f;
  float gx = 0.f;
  for (int sc=0; sc<14; sc++){
    gx += gxp[((size_t)b*14 + sc)*CC + d];
    const float* pb = part + ((size_t)b*14 + sc)*IC*CC + d;
    #pragma unroll
    for (int o=0;o<IC;o++) acc[o] += pb[(size_t)o*CC];
  }
  gx *= (1.f/196.f);
  #pragma unroll
  for (int o=0;o<IC;o++) acc[o] = fmaxf(wf[O_GGCS+o]*acc[o]+wf[O_GGCB+o], 0.f);
  float acc2 = 0.f;
  #pragma unroll
  for (int o2=0;o2<8;o2++){
    float tt = wf[O_WC1W + o2*33]*gx;
    #pragma unroll
    for (int o=0;o<IC;o++) tt += wf[O_WC1W + o2*33+1+o]*acc[o];
    float z = fmaxf(wf[O_WC1S+o2]*tt + wf[O_WC1B+o2], 0.f);
    acc2 += wf[O_WC2W+o2]*z;
  }
  c_att[idx] = sigf(wf[O_WC2S]*acc2 + wf[O_WC2B]);
}

// ---- k12 v3 (R16): out[b,c,p] = c_att[b,c]*x1tp[b,c,p], uint4-vectorized.
__global__ void k12_final(const int* flagp, const uint4* x1tp4,
                          const float* c_att, void* out)
{
  int i = blockIdx.x*256 + threadIdx.x;      // over 802816 uint4s, exact
  int flag = *flagp;
  uint4 v = x1tp4[i];
  float a = c_att[i/98];
  float f[8];
  f[0] = a*hb2f((unsigned short)(v.x & 0xffff));
  f[1] = a*hb2f((unsigned short)(v.x >> 16));
  f[2] = a*hb2f((unsigned short)(v.y & 0xffff));
  f[3] = a*hb2f((unsigned short)(v.y >> 16));
  f[4] = a*hb2f((unsigned short)(v.z & 0xffff));
  f[5] = a*hb2f((unsigned short)(v.z >> 16));
  f[6] = a*hb2f((unsigned short)(v.w & 0xffff));
  f[7] = a*hb2f((unsigned short)(v.w >> 16));
  if (flag){
    uint4 o;
    o.x = (unsigned)f2hb(f[0]) | ((unsigned)f2hb(f[1])<<16);
    o.y = (unsigned)f2hb(f[2]) | ((unsigned)f2hb(f[3])<<16);
    o.z = (unsigned)f2hb(f[4]) | ((unsigned)f2hb(f[5])<<16);
    o.w = (unsigned)f2hb(f[6]) | ((unsigned)f2hb(f[7])<<16);
    ((uint4*)out)[i] = o;
  } else {
    float4* op = (float4*)out + (size_t)i*2;
    op[0] = make_float4(f[0], f[1], f[2], f[3]);
    op[1] = make_float4(f[4], f[5], f[6], f[7]);
  }
}

extern "C" void kernel_launch(void* const* d_in, const int* in_sizes, int n_in,
                              void* d_out, int out_size, void* d_ws, size_t ws_size,
                              hipStream_t stream)
{
  const void* x = d_in[0];

  float* W = (float*)d_ws;
  int*   flag  = (int*)W;                    // W[0..63] reserved
  float* wf    = W + 64;                     // 800768
  float* theta = wf + WF_TOTAL;              // 1605632 (scratch; part alias)
  unsigned short* thph = (unsigned short*)(theta + 1605632); // 3211264 u16 (old phi slot)
  float* g_xs  = theta + 2*1605632;          // 50176
  float* Aphi  = g_xs + 50176;               // 401408 (acomb lives here)
  float* Atheta= Aphi + 401408;              // 401408
  unsigned short* acomb = (unsigned short*)Aphi;  // 64*208*64 u16 = 851968 (fits 802816 f32 x2)
  unsigned short* x1tp = (unsigned short*)(Atheta + 401408); // 6422528 u16 = 3211264 f32 slots
  float* thcp  = Atheta + 401408 + 3211264;  // 1605632
  float* phcp  = thcp + 1605632;             // 1605632
  float* gxcp  = phcp + 1605632;             // 1605632 (thcp/phcp/gxcp contiguous!)
  float* Bph   = gxcp + 1605632;             // 401408
  float* Bth   = Bph + 401408;               // 401408
  unsigned int* ws1bf32 = (unsigned int*)(Bth + 401408);  // 7168 u32 (slot 9664)
  float* c_att = (float*)(ws1bf32) + 9664;   // 8192
  unsigned short* wbf = (unsigned short*)(c_att + 8192);  // 780608 u16 (~53.9 MiB total)
  unsigned short* wggs = wbf + 3*IS*HW;      // 2*196*784 u16
  unsigned short* wthph = wbf + 5*IS*HW;     // 96*128 u16 (tail of wbf)
  // k10 partials reuse dead theta..Atheta region (4,064,256 contiguous floats):
  float* part = theta;                       // 64*14*32*128 = 3,670,016
  float* gxp  = theta + 3670016;             // 64*14*128  = 114,688 (fits: 3,784,704 < 4,064,256)

  ConvArgs ca;
  ca.cum[0] = 0;
  for (int i=0;i<36;i++){
    ca.p[i] = d_in[i+1];
    ca.cum[i+1] = ca.cum[i] + SRC_SIZES[i];
    ca.dst[i] = DST_OFF[i];
  }

  kd_detect<<<1, 256, 0, stream>>>(x, flag);
  kc_convert<<<(800716+255)/256, 256, 0, stream>>>(ca, flag, wf);
  kw_wbf<<<(KWK0_TOT+255)/256, 256, 0, stream>>>(wf, wbf, ws1bf32);
  k1k2_mfma<<<64*13, 256, 0, stream>>>(x, flag, wf, wthph, thph, g_xs);
  k3_mfma<<<2*64*2, 256, 0, stream>>>(wggs, thph, acomb);
  k4_mfma<<<64*13, 256, 0, stream>>>(x, flag, wf, thph, acomb,
      g_xs, ws1bf32, x1tp);
  k8_mfma<<<13*64, 256, 0, stream>>>(wbf, x1tp, wf, thcp);
  k9_bfact<<<2*64*4, 256, 0, stream>>>(wf, thcp, phcp, Bph, Bth);
  k10a_part<<<64*14, 256, 0, stream>>>(thcp, phcp, gxcp, Bph, Bth, part, gxp);
  k10b_catt<<<(BB*CC)/256, 256, 0, stream>>>(wf, part, gxp, c_att);
  k12_final<<<(BB*CC*HW/8)/256, 256, 0, stream>>>(flag, (const uint4*)x1tp,
      c_att, d_out);
}